// Round 1
// baseline (1546.126 us; speedup 1.0000x reference)
//
#include <hip/hip_runtime.h>
#include <math.h>

static constexpr int N  = 50000;
static constexpr int E  = 800000;
static constexpr int G  = 512;
static constexpr int D  = 128;
static constexpr int EF = 8;
static constexpr int EE = 64;
static constexpr int L  = 4;
static constexpr int NC = 10;

static constexpr size_t pad64(size_t w){ return (w + 63) & ~size_t(63); }
// workspace layout in 4-byte words; [O_LOOPRAW, ZERO_END) is zero-initialized
static constexpr size_t O_LOOPRAW = 0;                          // N*8 floats
static constexpr size_t O_CNT     = O_LOOPRAW + pad64((size_t)N*8); // N ints
static constexpr size_t O_CURSOR  = O_CNT + pad64(N);           // N ints
static constexpr size_t O_GSUM    = O_CURSOR + pad64(N);        // G*D floats
static constexpr size_t O_GCNT    = O_GSUM + pad64(G*D);        // G floats
static constexpr size_t ZERO_END  = O_GCNT + pad64(G);
static constexpr size_t O_SELFF   = ZERO_END;                   // N floats
static constexpr size_t O_CSROFF  = O_SELFF + pad64(N);         // N+1 ints
static constexpr size_t O_BSUM    = O_CSROFF + pad64(N+1);      // 64 ints
static constexpr size_t O_CSRE    = O_BSUM + 64;                // E ints
static constexpr size_t O_MFOLD   = O_CSRE + pad64(E);          // L*8*D floats
static constexpr size_t O_CFOLD   = O_MFOLD + pad64(L*8*D);     // L*D floats
static constexpr size_t O_X       = O_CFOLD + pad64(L*D);       // N*D floats
static constexpr size_t O_XL      = O_X  + pad64((size_t)N*D);
static constexpr size_t O_XR      = O_XL + pad64((size_t)N*D);

__global__ void zero_kernel(float* __restrict__ p, int n) {
    int i = blockIdx.x * blockDim.x + threadIdx.x;
    if (i < n) p[i] = 0.0f;
}

__global__ void embed_kernel(const int* __restrict__ xn, const float* __restrict__ emb,
                             float* __restrict__ x) {
    int i = blockIdx.x * blockDim.x + threadIdx.x;   // N*D
    int n = i >> 7, c = i & 127;
    if (n < N) x[i] = emb[xn[n] * D + c];
}

// Mfold[l][j][t] = sum_k edge_W[j][k] * We[l][k][t];  cfold[l][t] = sum_k edge_b[k]*We[l][k][t]
__global__ void fold_kernel(const float* __restrict__ edge_W, const float* __restrict__ edge_b,
                            const float* __restrict__ We, float* __restrict__ Mfold,
                            float* __restrict__ cfold) {
    int t = threadIdx.x;      // 128
    int l = blockIdx.x;       // 4
    const float* Wel = We + (size_t)l * EE * D;
    for (int j = 0; j < EF; ++j) {
        float s = 0.f;
        for (int k = 0; k < EE; ++k) s += edge_W[j * EE + k] * Wel[k * D + t];
        Mfold[(l * EF + j) * D + t] = s;
    }
    float s = 0.f;
    for (int k = 0; k < EE; ++k) s += edge_b[k] * Wel[k * D + t];
    cfold[l * D + t] = s;
}

__global__ void edge_stats_kernel(const int* __restrict__ src, const int* __restrict__ dst,
                                  const float* __restrict__ eattr,
                                  float* __restrict__ loopraw8, int* __restrict__ cnt) {
    int i = blockIdx.x * blockDim.x + threadIdx.x;   // E*8
    int e = i >> 3, j = i & 7;
    if (e >= E) return;
    int s = src[e], d = dst[e];
    if (s == d) return;
    atomicAdd(&loopraw8[d * 8 + j], eattr[e * 8 + j]);
    if (j == 0) atomicAdd(&cnt[d], 1);
}

__global__ void normalize_kernel(const int* __restrict__ cnt, float* __restrict__ loopraw8,
                                 float* __restrict__ selff) {
    int i = blockIdx.x * blockDim.x + threadIdx.x;   // N*8
    int n = i >> 3, j = i & 7;
    if (n >= N) return;
    int c = cnt[n];
    float inv = 1.0f / (float)(c > 1 ? c : 1);
    loopraw8[n * 8 + j] *= inv;
    if (j == 0) selff[n] = (c > 0) ? 1.0f : 0.0f;
}

// scan over cnt[N] -> csr_off (exclusive, csr_off[0]=0, csr_off[i+1]=inclusive[i])
__global__ void scan1_kernel(const int* __restrict__ cnt, int* __restrict__ out /*=csr_off+1*/,
                             int* __restrict__ bsum) {
    __shared__ int lds[256];
    int b = blockIdx.x, t = threadIdx.x;
    int base = b * 1024 + t * 4;
    int v[4]; int s = 0;
    #pragma unroll
    for (int k = 0; k < 4; ++k) { int idx = base + k; v[k] = (idx < N) ? cnt[idx] : 0; s += v[k]; }
    lds[t] = s; __syncthreads();
    for (int off = 1; off < 256; off <<= 1) {
        int add = (t >= off) ? lds[t - off] : 0;
        __syncthreads();
        lds[t] += add;
        __syncthreads();
    }
    int run = (t > 0) ? lds[t - 1] : 0;
    #pragma unroll
    for (int k = 0; k < 4; ++k) { run += v[k]; int idx = base + k; if (idx < N) out[idx] = run; }
    if (t == 255) bsum[b] = lds[255];
}

__global__ void scan2_kernel(int* __restrict__ bsum, int nb) {
    if (threadIdx.x == 0 && blockIdx.x == 0) {
        int run = 0;
        for (int i = 0; i < nb; ++i) { int v = bsum[i]; bsum[i] = run; run += v; }
    }
}

__global__ void scan3_kernel(int* __restrict__ csr_off, const int* __restrict__ bsum) {
    int i = blockIdx.x * blockDim.x + threadIdx.x;
    if (i == 0) csr_off[0] = 0;
    if (i < N) csr_off[1 + i] += bsum[i >> 10];
}

__global__ void csr_fill_kernel(const int* __restrict__ src, const int* __restrict__ dst,
                                const int* __restrict__ csr_off, int* __restrict__ cursor,
                                int* __restrict__ csr_edges) {
    int e = blockIdx.x * blockDim.x + threadIdx.x;
    if (e >= E) return;
    int s = src[e], d = dst[e];
    if (s == d) return;
    int pos = atomicAdd(&cursor[d], 1);
    csr_edges[csr_off[d] + pos] = e;
}

// xl = x@Wl + bl ; xr = x@Wr + br   (per layer). Block=128 threads (one out channel),
// NB=8 nodes per block; x row values are wave-uniform -> scalar loads.
__global__ __launch_bounds__(128) void transform_kernel(
        const float* __restrict__ x,
        const float* __restrict__ Wl, const float* __restrict__ bl,
        const float* __restrict__ Wr, const float* __restrict__ br,
        float* __restrict__ xl, float* __restrict__ xr) {
    constexpr int NB = 8;
    int t = threadIdx.x;
    int n0 = blockIdx.x * NB;
    float accl[NB], accr[NB];
    #pragma unroll
    for (int i = 0; i < NB; ++i) { accl[i] = 0.f; accr[i] = 0.f; }
    #pragma unroll 4
    for (int k = 0; k < D; ++k) {
        float wl = Wl[k * D + t];
        float wr = Wr[k * D + t];
        #pragma unroll
        for (int i = 0; i < NB; ++i) {
            float xv = x[(size_t)(n0 + i) * D + k];
            accl[i] += xv * wl;
            accr[i] += xv * wr;
        }
    }
    float blv = bl[t], brv = br[t];
    #pragma unroll
    for (int i = 0; i < NB; ++i) {
        xl[(size_t)(n0 + i) * D + t] = accl[i] + blv;
        xr[(size_t)(n0 + i) * D + t] = accr[i] + brv;
    }
}

__device__ __forceinline__ float red16(float v) {
    v += __shfl_xor(v, 1);
    v += __shfl_xor(v, 2);
    v += __shfl_xor(v, 4);
    v += __shfl_xor(v, 8);
    return v;
}

// One block (128 threads) per node: online segment-softmax + weighted aggregation.
__global__ __launch_bounds__(128) void aggregate_kernel(
        const float* __restrict__ xl, const float* __restrict__ xr,
        const float* __restrict__ loopraw8, const float* __restrict__ selff,
        const int* __restrict__ csr_off, const int* __restrict__ csr_edges,
        const int* __restrict__ esrc, const float* __restrict__ eattr,
        const float* __restrict__ Mfold, const float* __restrict__ cfold,
        const float* __restrict__ att, const float* __restrict__ gbias,
        const float* __restrict__ bn_gamma, const float* __restrict__ bn_beta,
        float* __restrict__ xout) {
    int n = blockIdx.x;
    int t = threadIdx.x;                 // 0..127 : channel; head = t>>4
    float attv = att[t];                 // att[l] pre-offset: [H][C] flat == t
    float Mreg[8];
    #pragma unroll
    for (int j = 0; j < 8; ++j) Mreg[j] = Mfold[j * D + t];
    float cf  = cfold[t];
    float xrv = xr[(size_t)n * D + t];
    float xlv = xl[(size_t)n * D + t];

    // self loop (edge attr = folded per-node mean)
    const float4* lr4 = reinterpret_cast<const float4*>(loopraw8 + (size_t)n * 8);
    float4 la = lr4[0], lb = lr4[1];
    float ep = cf * selff[n];
    ep += la.x * Mreg[0] + la.y * Mreg[1] + la.z * Mreg[2] + la.w * Mreg[3];
    ep += lb.x * Mreg[4] + lb.y * Mreg[5] + lb.z * Mreg[6] + lb.w * Mreg[7];
    float z = xlv + xrv + ep;
    z = z > 0.f ? z : 0.2f * z;
    float lg = red16(z * attv);
    float m = lg, denom = 1.0f, acc = xlv;

    int beg = csr_off[n], end = csr_off[n + 1];
    for (int idx = beg; idx < end; ++idx) {
        int e = csr_edges[idx];
        int s = esrc[e];
        const float4* ea4 = reinterpret_cast<const float4*>(eattr + (size_t)e * 8);
        float4 ea = ea4[0], eb = ea4[1];
        float ep2 = cf;
        ep2 += ea.x * Mreg[0] + ea.y * Mreg[1] + ea.z * Mreg[2] + ea.w * Mreg[3];
        ep2 += eb.x * Mreg[4] + eb.y * Mreg[5] + eb.z * Mreg[6] + eb.w * Mreg[7];
        float xls = xl[(size_t)s * D + t];
        float z2 = xls + xrv + ep2;
        z2 = z2 > 0.f ? z2 : 0.2f * z2;
        float lg2 = red16(z2 * attv);
        float nm = fmaxf(m, lg2);
        float wo = __expf(m - nm);
        float wn = __expf(lg2 - nm);
        denom = denom * wo + wn;
        acc   = acc * wo + wn * xls;
        m = nm;
    }
    float hv = acc / denom + gbias[t];
    hv = bn_gamma[t] * hv * 0.999995000037499813f + bn_beta[t];
    xout[(size_t)n * D + t] = hv > 0.f ? hv : (__expf(hv) - 1.0f);
}

__global__ void pool_kernel(const float* __restrict__ x, const int* __restrict__ batch,
                            float* __restrict__ gsum, float* __restrict__ gcnt) {
    int i = blockIdx.x * blockDim.x + threadIdx.x;   // N*D
    int n = i >> 7, c = i & 127;
    if (n >= N) return;
    int g = batch[n];
    atomicAdd(&gsum[(size_t)g * D + c], x[i]);
    if (c == 0) atomicAdd(&gcnt[g], 1.0f);
}

__global__ __launch_bounds__(64) void head_kernel(
        const float* __restrict__ gsum, const float* __restrict__ gcnt,
        const float* __restrict__ hW, const float* __restrict__ hb,
        float* __restrict__ out) {
    int g = blockIdx.x;
    int t = threadIdx.x;   // 64
    float inv = 1.0f / fmaxf(gcnt[g], 1.0f);
    float v0 = gsum[(size_t)g * D + t] * inv;
    float v1 = gsum[(size_t)g * D + 64 + t] * inv;
    for (int k = 0; k < NC; ++k) {
        float p = v0 * hW[t * NC + k] + v1 * hW[(t + 64) * NC + k];
        p += __shfl_xor(p, 1);  p += __shfl_xor(p, 2);  p += __shfl_xor(p, 4);
        p += __shfl_xor(p, 8);  p += __shfl_xor(p, 16); p += __shfl_xor(p, 32);
        if (t == 0) out[g * NC + k] = p + hb[k];
    }
}

extern "C" void kernel_launch(void* const* d_in, const int* in_sizes, int n_in,
                              void* d_out, int out_size, void* d_ws, size_t ws_size,
                              hipStream_t stream) {
    const int*   x_nodes   = (const int*)  d_in[0];
    const int*   edge_src  = (const int*)  d_in[1];
    const int*   edge_dst  = (const int*)  d_in[2];
    const float* edge_attr = (const float*)d_in[3];
    const int*   batch     = (const int*)  d_in[4];
    const float* node_emb  = (const float*)d_in[5];
    const float* edge_W    = (const float*)d_in[6];
    const float* edge_b    = (const float*)d_in[7];
    const float* Wl        = (const float*)d_in[8];
    const float* bl        = (const float*)d_in[9];
    const float* Wr        = (const float*)d_in[10];
    const float* br        = (const float*)d_in[11];
    const float* We        = (const float*)d_in[12];
    const float* att       = (const float*)d_in[13];
    const float* gbias     = (const float*)d_in[14];
    const float* bn_gamma  = (const float*)d_in[15];
    const float* bn_beta   = (const float*)d_in[16];
    const float* head_W    = (const float*)d_in[17];
    const float* head_b    = (const float*)d_in[18];
    float* out = (float*)d_out;

    float* ws = (float*)d_ws;
    float* loopraw8 = ws + O_LOOPRAW;
    int*   cnt      = (int*)(ws + O_CNT);
    int*   cursor   = (int*)(ws + O_CURSOR);
    float* gsum     = ws + O_GSUM;
    float* gcnt     = ws + O_GCNT;
    float* selff    = ws + O_SELFF;
    int*   csr_off  = (int*)(ws + O_CSROFF);
    int*   bsum     = (int*)(ws + O_BSUM);
    int*   csr_edges= (int*)(ws + O_CSRE);
    float* Mfold    = ws + O_MFOLD;
    float* cfold    = ws + O_CFOLD;
    float* x  = ws + O_X;
    float* xl = ws + O_XL;
    float* xr = ws + O_XR;

    // 1) zero accumulator regions
    {
        int nz = (int)ZERO_END;
        zero_kernel<<<(nz + 255) / 256, 256, 0, stream>>>(ws, nz);
    }
    // 2) node embedding
    embed_kernel<<<(N * D + 255) / 256, 256, 0, stream>>>(x_nodes, node_emb, x);
    // 3) folded edge transforms
    fold_kernel<<<L, D, 0, stream>>>(edge_W, edge_b, We, Mfold, cfold);
    // 4) per-dst incoming stats (count + mean raw edge attr)
    edge_stats_kernel<<<(E * 8 + 255) / 256, 256, 0, stream>>>(edge_src, edge_dst, edge_attr,
                                                               loopraw8, cnt);
    // 5) normalize means + self-loop flag
    normalize_kernel<<<(N * 8 + 255) / 256, 256, 0, stream>>>(cnt, loopraw8, selff);
    // 6) exclusive scan -> csr_off
    {
        int nb = (N + 1023) / 1024;   // 49
        scan1_kernel<<<nb, 256, 0, stream>>>(cnt, csr_off + 1, bsum);
        scan2_kernel<<<1, 64, 0, stream>>>(bsum, nb);
        scan3_kernel<<<(N + 255) / 256, 256, 0, stream>>>(csr_off, bsum);
    }
    // 7) CSR scatter
    csr_fill_kernel<<<(E + 255) / 256, 256, 0, stream>>>(edge_src, edge_dst, csr_off,
                                                         cursor, csr_edges);
    // 8) GAT layers
    for (int l = 0; l < L; ++l) {
        transform_kernel<<<N / 8, 128, 0, stream>>>(
            x, Wl + (size_t)l * D * D, bl + l * D, Wr + (size_t)l * D * D, br + l * D, xl, xr);
        aggregate_kernel<<<N, 128, 0, stream>>>(
            xl, xr, loopraw8, selff, csr_off, csr_edges, edge_src, edge_attr,
            Mfold + (size_t)l * EF * D, cfold + l * D, att + l * D, gbias + l * D,
            bn_gamma + l * D, bn_beta + l * D, x);
    }
    // 9) global mean pool
    pool_kernel<<<(N * D + 255) / 256, 256, 0, stream>>>(x, batch, gsum, gcnt);
    // 10) classifier head
    head_kernel<<<G, 64, 0, stream>>>(gsum, gcnt, head_W, head_b, out);

    (void)in_sizes; (void)n_in; (void)out_size; (void)ws_size;
}

// Round 2
// 1025.140 us; speedup vs baseline: 1.5082x; 1.5082x over previous
//
#include <hip/hip_runtime.h>
#include <hip/hip_fp16.h>
#include <math.h>

static constexpr int N  = 50000;
static constexpr int E  = 800000;
static constexpr int G  = 512;
static constexpr int D  = 128;
static constexpr int EF = 8;
static constexpr int EE = 64;
static constexpr int L  = 4;
static constexpr int NC = 10;

static constexpr size_t pad64(size_t w){ return (w + 63) & ~size_t(63); }
// workspace layout in 4-byte words; [O_LOOPRAW, ZERO_END) is zero-initialized
static constexpr size_t O_LOOPRAW = 0;                              // N*8 floats
static constexpr size_t O_CNT     = O_LOOPRAW + pad64((size_t)N*8); // N ints
static constexpr size_t O_CURSOR  = O_CNT + pad64(N);               // N ints
static constexpr size_t O_GSUM    = O_CURSOR + pad64(N);            // G*D floats
static constexpr size_t O_GCNT    = O_GSUM + pad64(G*D);            // G floats
static constexpr size_t ZERO_END  = O_GCNT + pad64(G);
static constexpr size_t O_SELFF   = ZERO_END;                       // N floats
static constexpr size_t O_CSROFF  = O_SELFF + pad64(N);             // N+1 ints
static constexpr size_t O_BSUM    = O_CSROFF + pad64(N+1);          // 64 ints
static constexpr size_t O_CSRSRC  = O_BSUM + 64;                    // E ints
static constexpr size_t O_CSREA   = O_CSRSRC + pad64(E);            // E*8 halfs = E*4 words
static constexpr size_t O_MFOLD   = O_CSREA + pad64((size_t)E*4);   // L*8*D floats
static constexpr size_t O_CFOLD   = O_MFOLD + pad64(L*8*D);         // L*D floats
static constexpr size_t O_X       = O_CFOLD + pad64(L*D);           // N*D floats
static constexpr size_t O_XLH     = O_X + pad64((size_t)N*D);       // N*D halfs = N*64 words
static constexpr size_t O_XR      = O_XLH + pad64((size_t)N*(D/2)); // N*D floats

__global__ void zero_kernel(float* __restrict__ p, int n) {
    int i = blockIdx.x * blockDim.x + threadIdx.x;
    if (i < n) p[i] = 0.0f;
}

__global__ void embed_kernel(const int* __restrict__ xn, const float* __restrict__ emb,
                             float* __restrict__ x) {
    int i = blockIdx.x * blockDim.x + threadIdx.x;   // N*D
    int n = i >> 7, c = i & 127;
    if (n < N) x[i] = emb[xn[n] * D + c];
}

// Mfold[l][j][t] = sum_k edge_W[j][k] * We[l][k][t];  cfold[l][t] = sum_k edge_b[k]*We[l][k][t]
__global__ void fold_kernel(const float* __restrict__ edge_W, const float* __restrict__ edge_b,
                            const float* __restrict__ We, float* __restrict__ Mfold,
                            float* __restrict__ cfold) {
    int t = threadIdx.x;      // 128
    int l = blockIdx.x;       // 4
    const float* Wel = We + (size_t)l * EE * D;
    for (int j = 0; j < EF; ++j) {
        float s = 0.f;
        for (int k = 0; k < EE; ++k) s += edge_W[j * EE + k] * Wel[k * D + t];
        Mfold[(l * EF + j) * D + t] = s;
    }
    float s = 0.f;
    for (int k = 0; k < EE; ++k) s += edge_b[k] * Wel[k * D + t];
    cfold[l * D + t] = s;
}

__global__ void edge_stats_kernel(const int* __restrict__ src, const int* __restrict__ dst,
                                  const float* __restrict__ eattr,
                                  float* __restrict__ loopraw8, int* __restrict__ cnt) {
    int i = blockIdx.x * blockDim.x + threadIdx.x;   // E*8
    int e = i >> 3, j = i & 7;
    if (e >= E) return;
    int s = src[e], d = dst[e];
    if (s == d) return;
    atomicAdd(&loopraw8[d * 8 + j], eattr[e * 8 + j]);
    if (j == 0) atomicAdd(&cnt[d], 1);
}

__global__ void normalize_kernel(const int* __restrict__ cnt, float* __restrict__ loopraw8,
                                 float* __restrict__ selff) {
    int i = blockIdx.x * blockDim.x + threadIdx.x;   // N*8
    int n = i >> 3, j = i & 7;
    if (n >= N) return;
    int c = cnt[n];
    float inv = 1.0f / (float)(c > 1 ? c : 1);
    loopraw8[n * 8 + j] *= inv;
    if (j == 0) selff[n] = (c > 0) ? 1.0f : 0.0f;
}

// scan over cnt[N] -> csr_off (exclusive, csr_off[0]=0, csr_off[i+1]=inclusive[i])
__global__ void scan1_kernel(const int* __restrict__ cnt, int* __restrict__ out /*=csr_off+1*/,
                             int* __restrict__ bsum) {
    __shared__ int lds[256];
    int b = blockIdx.x, t = threadIdx.x;
    int base = b * 1024 + t * 4;
    int v[4]; int s = 0;
    #pragma unroll
    for (int k = 0; k < 4; ++k) { int idx = base + k; v[k] = (idx < N) ? cnt[idx] : 0; s += v[k]; }
    lds[t] = s; __syncthreads();
    for (int off = 1; off < 256; off <<= 1) {
        int add = (t >= off) ? lds[t - off] : 0;
        __syncthreads();
        lds[t] += add;
        __syncthreads();
    }
    int run = (t > 0) ? lds[t - 1] : 0;
    #pragma unroll
    for (int k = 0; k < 4; ++k) { run += v[k]; int idx = base + k; if (idx < N) out[idx] = run; }
    if (t == 255) bsum[b] = lds[255];
}

__global__ void scan2_kernel(int* __restrict__ bsum, int nb) {
    if (threadIdx.x == 0 && blockIdx.x == 0) {
        int run = 0;
        for (int i = 0; i < nb; ++i) { int v = bsum[i]; bsum[i] = run; run += v; }
    }
}

__global__ void scan3_kernel(int* __restrict__ csr_off, const int* __restrict__ bsum) {
    int i = blockIdx.x * blockDim.x + threadIdx.x;
    if (i == 0) csr_off[0] = 0;
    if (i < N) csr_off[1 + i] += bsum[i >> 10];
}

// CSR fill with src id and fp16 edge attr inlined (removes two indirections in aggregate)
__global__ void csr_fill_kernel(const int* __restrict__ src, const int* __restrict__ dst,
                                const float* __restrict__ eattr,
                                const int* __restrict__ csr_off, int* __restrict__ cursor,
                                int* __restrict__ csr_src, __half* __restrict__ csr_ea) {
    int e = blockIdx.x * blockDim.x + threadIdx.x;
    if (e >= E) return;
    int s = src[e], d = dst[e];
    if (s == d) return;
    int pos = csr_off[d] + atomicAdd(&cursor[d], 1);
    csr_src[pos] = s;
    const float4* p = reinterpret_cast<const float4*>(eattr + (size_t)e * 8);
    float4 a = p[0], b = p[1];
    __half2 h[4];
    h[0] = __floats2half2_rn(a.x, a.y); h[1] = __floats2half2_rn(a.z, a.w);
    h[2] = __floats2half2_rn(b.x, b.y); h[3] = __floats2half2_rn(b.z, b.w);
    *reinterpret_cast<float4*>(csr_ea + (size_t)pos * 8) = *reinterpret_cast<const float4*>(h);
}

// xl = x@Wl + bl (fp16 out) ; xr = x@Wr + br (f32 out). Block=128 threads (one out channel),
// NB=8 nodes per block; x row values are wave-uniform -> scalar loads.
__global__ __launch_bounds__(128) void transform_kernel(
        const float* __restrict__ x,
        const float* __restrict__ Wl, const float* __restrict__ bl,
        const float* __restrict__ Wr, const float* __restrict__ br,
        __half* __restrict__ xl_h, float* __restrict__ xr) {
    constexpr int NB = 8;
    int t = threadIdx.x;
    int n0 = blockIdx.x * NB;
    float accl[NB], accr[NB];
    #pragma unroll
    for (int i = 0; i < NB; ++i) { accl[i] = 0.f; accr[i] = 0.f; }
    #pragma unroll 4
    for (int k = 0; k < D; ++k) {
        float wl = Wl[k * D + t];
        float wr = Wr[k * D + t];
        #pragma unroll
        for (int i = 0; i < NB; ++i) {
            float xv = x[(size_t)(n0 + i) * D + k];
            accl[i] += xv * wl;
            accr[i] += xv * wr;
        }
    }
    float blv = bl[t], brv = br[t];
    #pragma unroll
    for (int i = 0; i < NB; ++i) {
        xl_h[(size_t)(n0 + i) * D + t] = __float2half_rn(accl[i] + blv);
        xr[(size_t)(n0 + i) * D + t] = accr[i] + brv;
    }
}

__device__ __forceinline__ void load8h(const __half* p, float o[8]) {
    float4 v = *reinterpret_cast<const float4*>(p);
    const __half2* h = reinterpret_cast<const __half2*>(&v);
    #pragma unroll
    for (int k = 0; k < 4; ++k) {
        float2 f = __half22float2(h[k]);
        o[2 * k] = f.x; o[2 * k + 1] = f.y;
    }
}

// One wave per node (2 nodes / 128-block). Thread = 2 channels via half2.
// Online segment-softmax + weighted aggregation; edge loop unrolled x2 so two
// independent xl gathers are in flight.
__global__ __launch_bounds__(128) void aggregate_kernel(
        const __half* __restrict__ xl_h, const float* __restrict__ xr,
        const float* __restrict__ loopraw8, const float* __restrict__ selff,
        const int* __restrict__ csr_off, const int* __restrict__ csr_src,
        const __half* __restrict__ csr_ea,
        const float* __restrict__ Mfold, const float* __restrict__ cfold,
        const float* __restrict__ att, const float* __restrict__ gbias,
        const float* __restrict__ bn_gamma, const float* __restrict__ bn_beta,
        float* __restrict__ xout) {
    int n = blockIdx.x * 2 + (threadIdx.x >> 6);
    int t = threadIdx.x & 63;        // lane in wave
    int c0 = t * 2;                  // two channels c0, c0+1; head = t>>3 (8 lanes/head)
    float att0 = att[c0], att1 = att[c0 + 1];
    float M0[8], M1[8];
    #pragma unroll
    for (int j = 0; j < 8; ++j) { M0[j] = Mfold[j * D + c0]; M1[j] = Mfold[j * D + c0 + 1]; }
    float cf0 = cfold[c0], cf1 = cfold[c0 + 1];
    float2 xrv = *reinterpret_cast<const float2*>(xr + (size_t)n * D + c0);
    float2 xlv = __half22float2(*reinterpret_cast<const __half2*>(xl_h + (size_t)n * D + c0));

    // self loop (edge attr = folded per-node mean of incoming raw attrs)
    float la[8];
    {
        const float4* p = reinterpret_cast<const float4*>(loopraw8 + (size_t)n * 8);
        float4 a = p[0], b = p[1];
        la[0] = a.x; la[1] = a.y; la[2] = a.z; la[3] = a.w;
        la[4] = b.x; la[5] = b.y; la[6] = b.z; la[7] = b.w;
    }
    float sf = selff[n];
    float ep0 = cf0 * sf, ep1 = cf1 * sf;
    #pragma unroll
    for (int j = 0; j < 8; ++j) { ep0 += la[j] * M0[j]; ep1 += la[j] * M1[j]; }
    float z0 = xlv.x + xrv.x + ep0; z0 = z0 > 0.f ? z0 : 0.2f * z0;
    float z1 = xlv.y + xrv.y + ep1; z1 = z1 > 0.f ? z1 : 0.2f * z1;
    float lg = z0 * att0 + z1 * att1;
    lg += __shfl_xor(lg, 1); lg += __shfl_xor(lg, 2); lg += __shfl_xor(lg, 4);
    float m = lg, denom = 1.0f, acc0 = xlv.x, acc1 = xlv.y;

    int beg = csr_off[n], end = csr_off[n + 1];
    int idx = beg;
    for (; idx + 2 <= end; idx += 2) {
        int s0 = csr_src[idx], s1 = csr_src[idx + 1];
        __half2 g0 = *reinterpret_cast<const __half2*>(xl_h + (size_t)s0 * D + c0);
        __half2 g1 = *reinterpret_cast<const __half2*>(xl_h + (size_t)s1 * D + c0);
        float ea0[8], ea1[8];
        load8h(csr_ea + (size_t)idx * 8, ea0);
        load8h(csr_ea + (size_t)idx * 8 + 8, ea1);
        float e00 = cf0, e01 = cf1, e10 = cf0, e11 = cf1;
        #pragma unroll
        for (int j = 0; j < 8; ++j) {
            e00 += ea0[j] * M0[j]; e01 += ea0[j] * M1[j];
            e10 += ea1[j] * M0[j]; e11 += ea1[j] * M1[j];
        }
        float2 x0 = __half22float2(g0), x1 = __half22float2(g1);
        float za = x0.x + xrv.x + e00; za = za > 0.f ? za : 0.2f * za;
        float zb = x0.y + xrv.y + e01; zb = zb > 0.f ? zb : 0.2f * zb;
        float zc = x1.x + xrv.x + e10; zc = zc > 0.f ? zc : 0.2f * zc;
        float zd = x1.y + xrv.y + e11; zd = zd > 0.f ? zd : 0.2f * zd;
        float l0 = za * att0 + zb * att1;
        float l1 = zc * att0 + zd * att1;
        l0 += __shfl_xor(l0, 1); l0 += __shfl_xor(l0, 2); l0 += __shfl_xor(l0, 4);
        l1 += __shfl_xor(l1, 1); l1 += __shfl_xor(l1, 2); l1 += __shfl_xor(l1, 4);
        float nm = fmaxf(m, fmaxf(l0, l1));
        float wo = __expf(m - nm), w0 = __expf(l0 - nm), w1 = __expf(l1 - nm);
        denom = denom * wo + w0 + w1;
        acc0 = acc0 * wo + w0 * x0.x + w1 * x1.x;
        acc1 = acc1 * wo + w0 * x0.y + w1 * x1.y;
        m = nm;
    }
    if (idx < end) {
        int s0 = csr_src[idx];
        __half2 g0 = *reinterpret_cast<const __half2*>(xl_h + (size_t)s0 * D + c0);
        float ea0[8];
        load8h(csr_ea + (size_t)idx * 8, ea0);
        float e00 = cf0, e01 = cf1;
        #pragma unroll
        for (int j = 0; j < 8; ++j) { e00 += ea0[j] * M0[j]; e01 += ea0[j] * M1[j]; }
        float2 x0 = __half22float2(g0);
        float za = x0.x + xrv.x + e00; za = za > 0.f ? za : 0.2f * za;
        float zb = x0.y + xrv.y + e01; zb = zb > 0.f ? zb : 0.2f * zb;
        float l0 = za * att0 + zb * att1;
        l0 += __shfl_xor(l0, 1); l0 += __shfl_xor(l0, 2); l0 += __shfl_xor(l0, 4);
        float nm = fmaxf(m, l0);
        float wo = __expf(m - nm), w0 = __expf(l0 - nm);
        denom = denom * wo + w0;
        acc0 = acc0 * wo + w0 * x0.x;
        acc1 = acc1 * wo + w0 * x0.y;
        m = nm;
    }
    float inv = 1.0f / denom;
    float h0 = acc0 * inv + gbias[c0];
    float h1 = acc1 * inv + gbias[c0 + 1];
    h0 = bn_gamma[c0] * h0 * 0.999995000037499813f + bn_beta[c0];
    h1 = bn_gamma[c0 + 1] * h1 * 0.999995000037499813f + bn_beta[c0 + 1];
    float2 o;
    o.x = h0 > 0.f ? h0 : (__expf(h0) - 1.0f);
    o.y = h1 > 0.f ? h1 : (__expf(h1) - 1.0f);
    *reinterpret_cast<float2*>(xout + (size_t)n * D + c0) = o;
}

__global__ void pool_kernel(const float* __restrict__ x, const int* __restrict__ batch,
                            float* __restrict__ gsum, float* __restrict__ gcnt) {
    int i = blockIdx.x * blockDim.x + threadIdx.x;   // N*D
    int n = i >> 7, c = i & 127;
    if (n >= N) return;
    int g = batch[n];
    atomicAdd(&gsum[(size_t)g * D + c], x[i]);
    if (c == 0) atomicAdd(&gcnt[g], 1.0f);
}

__global__ __launch_bounds__(64) void head_kernel(
        const float* __restrict__ gsum, const float* __restrict__ gcnt,
        const float* __restrict__ hW, const float* __restrict__ hb,
        float* __restrict__ out) {
    int g = blockIdx.x;
    int t = threadIdx.x;   // 64
    float inv = 1.0f / fmaxf(gcnt[g], 1.0f);
    float v0 = gsum[(size_t)g * D + t] * inv;
    float v1 = gsum[(size_t)g * D + 64 + t] * inv;
    for (int k = 0; k < NC; ++k) {
        float p = v0 * hW[t * NC + k] + v1 * hW[(t + 64) * NC + k];
        p += __shfl_xor(p, 1);  p += __shfl_xor(p, 2);  p += __shfl_xor(p, 4);
        p += __shfl_xor(p, 8);  p += __shfl_xor(p, 16); p += __shfl_xor(p, 32);
        if (t == 0) out[g * NC + k] = p + hb[k];
    }
}

extern "C" void kernel_launch(void* const* d_in, const int* in_sizes, int n_in,
                              void* d_out, int out_size, void* d_ws, size_t ws_size,
                              hipStream_t stream) {
    const int*   x_nodes   = (const int*)  d_in[0];
    const int*   edge_src  = (const int*)  d_in[1];
    const int*   edge_dst  = (const int*)  d_in[2];
    const float* edge_attr = (const float*)d_in[3];
    const int*   batch     = (const int*)  d_in[4];
    const float* node_emb  = (const float*)d_in[5];
    const float* edge_W    = (const float*)d_in[6];
    const float* edge_b    = (const float*)d_in[7];
    const float* Wl        = (const float*)d_in[8];
    const float* bl        = (const float*)d_in[9];
    const float* Wr        = (const float*)d_in[10];
    const float* br        = (const float*)d_in[11];
    const float* We        = (const float*)d_in[12];
    const float* att       = (const float*)d_in[13];
    const float* gbias     = (const float*)d_in[14];
    const float* bn_gamma  = (const float*)d_in[15];
    const float* bn_beta   = (const float*)d_in[16];
    const float* head_W    = (const float*)d_in[17];
    const float* head_b    = (const float*)d_in[18];
    float* out = (float*)d_out;

    float* ws = (float*)d_ws;
    float* loopraw8 = ws + O_LOOPRAW;
    int*   cnt      = (int*)(ws + O_CNT);
    int*   cursor   = (int*)(ws + O_CURSOR);
    float* gsum     = ws + O_GSUM;
    float* gcnt     = ws + O_GCNT;
    float* selff    = ws + O_SELFF;
    int*   csr_off  = (int*)(ws + O_CSROFF);
    int*   bsum     = (int*)(ws + O_BSUM);
    int*   csr_src  = (int*)(ws + O_CSRSRC);
    __half* csr_ea  = (__half*)(ws + O_CSREA);
    float* Mfold    = ws + O_MFOLD;
    float* cfold    = ws + O_CFOLD;
    float* x    = ws + O_X;
    __half* xl_h = (__half*)(ws + O_XLH);
    float* xr   = ws + O_XR;

    // 1) zero accumulator regions
    {
        int nz = (int)ZERO_END;
        zero_kernel<<<(nz + 255) / 256, 256, 0, stream>>>(ws, nz);
    }
    // 2) node embedding
    embed_kernel<<<(N * D + 255) / 256, 256, 0, stream>>>(x_nodes, node_emb, x);
    // 3) folded edge transforms
    fold_kernel<<<L, D, 0, stream>>>(edge_W, edge_b, We, Mfold, cfold);
    // 4) per-dst incoming stats (count + mean raw edge attr)
    edge_stats_kernel<<<(E * 8 + 255) / 256, 256, 0, stream>>>(edge_src, edge_dst, edge_attr,
                                                               loopraw8, cnt);
    // 5) normalize means + self-loop flag
    normalize_kernel<<<(N * 8 + 255) / 256, 256, 0, stream>>>(cnt, loopraw8, selff);
    // 6) exclusive scan -> csr_off
    {
        int nb = (N + 1023) / 1024;   // 49
        scan1_kernel<<<nb, 256, 0, stream>>>(cnt, csr_off + 1, bsum);
        scan2_kernel<<<1, 64, 0, stream>>>(bsum, nb);
        scan3_kernel<<<(N + 255) / 256, 256, 0, stream>>>(csr_off, bsum);
    }
    // 7) CSR scatter (src + fp16 edge attrs inline)
    csr_fill_kernel<<<(E + 255) / 256, 256, 0, stream>>>(edge_src, edge_dst, edge_attr,
                                                         csr_off, cursor, csr_src, csr_ea);
    // 8) GAT layers
    for (int l = 0; l < L; ++l) {
        transform_kernel<<<N / 8, 128, 0, stream>>>(
            x, Wl + (size_t)l * D * D, bl + l * D, Wr + (size_t)l * D * D, br + l * D, xl_h, xr);
        aggregate_kernel<<<N / 2, 128, 0, stream>>>(
            xl_h, xr, loopraw8, selff, csr_off, csr_src, csr_ea,
            Mfold + (size_t)l * EF * D, cfold + l * D, att + l * D, gbias + l * D,
            bn_gamma + l * D, bn_beta + l * D, x);
    }
    // 9) global mean pool
    pool_kernel<<<(N * D + 255) / 256, 256, 0, stream>>>(x, batch, gsum, gcnt);
    // 10) classifier head
    head_kernel<<<G, 64, 0, stream>>>(gsum, gcnt, head_W, head_b, out);

    (void)in_sizes; (void)n_in; (void)out_size; (void)ws_size;
}

// Round 3
// 720.023 us; speedup vs baseline: 2.1473x; 1.4238x over previous
//
#include <hip/hip_runtime.h>
#include <hip/hip_fp16.h>
#include <math.h>

static constexpr int N  = 50000;
static constexpr int E  = 800000;
static constexpr int G  = 512;
static constexpr int D  = 128;
static constexpr int EF = 8;
static constexpr int EE = 64;
static constexpr int L  = 4;
static constexpr int NC = 10;

typedef _Float16 half8 __attribute__((ext_vector_type(8)));
typedef float f32x4 __attribute__((ext_vector_type(4)));

static constexpr size_t pad64(size_t w){ return (w + 63) & ~size_t(63); }
// workspace layout in 4-byte words; [0, ZERO_END) is zero-initialized
static constexpr size_t O_CNT     = 0;                               // N ints
static constexpr size_t O_CURSOR  = O_CNT + pad64(N);                // N ints
static constexpr size_t ZERO_END  = O_CURSOR + pad64(N);
static constexpr size_t O_CSROFF  = ZERO_END;                        // N+1 ints
static constexpr size_t O_BSUM    = O_CSROFF + pad64(N+1);           // 64 ints
static constexpr size_t O_CSRSRC  = O_BSUM + 64;                     // E ints
static constexpr size_t O_CSREA   = O_CSRSRC + pad64(E);             // E*8 halfs = E*4 words
static constexpr size_t O_MFOLD   = O_CSREA + pad64((size_t)E*4);    // L*8*D f32
static constexpr size_t O_CFOLD   = O_MFOLD + pad64(L*8*D);          // L*D f32
static constexpr size_t O_LOOPM   = O_CFOLD + pad64(L*D);            // N*8 f32
static constexpr size_t O_SELFF   = O_LOOPM + pad64((size_t)N*8);    // N f32
static constexpr size_t O_WFRAG   = O_SELFF + pad64(N);              // L*32768 halfs = L*16384 words
static constexpr size_t O_XH      = O_WFRAG + pad64((size_t)L*16384);// N*D halfs
static constexpr size_t O_XLH     = O_XH  + pad64((size_t)N*64);
static constexpr size_t O_XRH     = O_XLH + pad64((size_t)N*64);

__global__ void zero_kernel(float* __restrict__ p, int n) {
    int i = blockIdx.x * blockDim.x + threadIdx.x;
    if (i < n) p[i] = 0.0f;
}

__global__ void embed_kernel(const int* __restrict__ xn, const float* __restrict__ emb,
                             __half* __restrict__ xh) {
    int i = blockIdx.x * blockDim.x + threadIdx.x;   // N*D
    int n = i >> 7, c = i & 127;
    if (n < N) xh[i] = __float2half_rn(emb[xn[n] * D + c]);
}

// Mfold[l][j][t] = sum_k edge_W[j][k] * We[l][k][t];  cfold[l][t] = sum_k edge_b[k]*We[l][k][t]
__global__ void fold_kernel(const float* __restrict__ edge_W, const float* __restrict__ edge_b,
                            const float* __restrict__ We, float* __restrict__ Mfold,
                            float* __restrict__ cfold) {
    int t = threadIdx.x;      // 128
    int l = blockIdx.x;       // 4
    const float* Wel = We + (size_t)l * EE * D;
    for (int j = 0; j < EF; ++j) {
        float s = 0.f;
        for (int k = 0; k < EE; ++k) s += edge_W[j * EE + k] * Wel[k * D + t];
        Mfold[(l * EF + j) * D + t] = s;
    }
    float s = 0.f;
    for (int k = 0; k < EE; ++k) s += edge_b[k] * Wel[k * D + t];
    cfold[l * D + t] = s;
}

// Build fragment-ordered fp16 weights Wcat = [Wl | Wr] (128 x 256) per layer.
// Layout: [l][kt(4)][ntile(16)][lane(64)][j(8)], element = Wcat[kt*32+(lane>>4)*8+j][ntile*16+(lane&15)]
__global__ void wcvt_kernel(const float* __restrict__ Wl, const float* __restrict__ Wr,
                            _Float16* __restrict__ wfrag) {
    int i = blockIdx.x * blockDim.x + threadIdx.x;   // L*32768
    if (i >= L * 32768) return;
    int j    = i & 7;
    int lane = (i >> 3) & 63;
    int nt   = (i >> 9) & 15;
    int kt   = (i >> 13) & 3;
    int l    = i >> 15;
    int k = kt * 32 + (lane >> 4) * 8 + j;
    int n = nt * 16 + (lane & 15);
    float v = (n < 128) ? Wl[((size_t)l * D + k) * D + n]
                        : Wr[((size_t)l * D + k) * D + (n - 128)];
    wfrag[i] = (_Float16)v;
}

__global__ void edge_cnt_kernel(const int* __restrict__ src, const int* __restrict__ dst,
                                int* __restrict__ cnt) {
    int e = blockIdx.x * blockDim.x + threadIdx.x;
    if (e >= E) return;
    if (src[e] != dst[e]) atomicAdd(&cnt[dst[e]], 1);
}

// scan over cnt[N] -> csr_off (exclusive, csr_off[0]=0, csr_off[i+1]=inclusive[i])
__global__ void scan1_kernel(const int* __restrict__ cnt, int* __restrict__ out /*=csr_off+1*/,
                             int* __restrict__ bsum) {
    __shared__ int lds[256];
    int b = blockIdx.x, t = threadIdx.x;
    int base = b * 1024 + t * 4;
    int v[4]; int s = 0;
    #pragma unroll
    for (int k = 0; k < 4; ++k) { int idx = base + k; v[k] = (idx < N) ? cnt[idx] : 0; s += v[k]; }
    lds[t] = s; __syncthreads();
    for (int off = 1; off < 256; off <<= 1) {
        int add = (t >= off) ? lds[t - off] : 0;
        __syncthreads();
        lds[t] += add;
        __syncthreads();
    }
    int run = (t > 0) ? lds[t - 1] : 0;
    #pragma unroll
    for (int k = 0; k < 4; ++k) { run += v[k]; int idx = base + k; if (idx < N) out[idx] = run; }
    if (t == 255) bsum[b] = lds[255];
}

__global__ void scan2_kernel(int* __restrict__ bsum, int nb) {
    if (threadIdx.x == 0 && blockIdx.x == 0) {
        int run = 0;
        for (int i = 0; i < nb; ++i) { int v = bsum[i]; bsum[i] = run; run += v; }
    }
}

__global__ void scan3_kernel(int* __restrict__ csr_off, const int* __restrict__ bsum) {
    int i = blockIdx.x * blockDim.x + threadIdx.x;
    if (i == 0) csr_off[0] = 0;
    if (i < N) csr_off[1 + i] += bsum[i >> 10];
}

// CSR fill with src id and fp16 edge attr inlined
__global__ void csr_fill_kernel(const int* __restrict__ src, const int* __restrict__ dst,
                                const float* __restrict__ eattr,
                                const int* __restrict__ csr_off, int* __restrict__ cursor,
                                int* __restrict__ csr_src, __half* __restrict__ csr_ea) {
    int e = blockIdx.x * blockDim.x + threadIdx.x;
    if (e >= E) return;
    int s = src[e], d = dst[e];
    if (s == d) return;
    int pos = csr_off[d] + atomicAdd(&cursor[d], 1);
    csr_src[pos] = s;
    const float4* p = reinterpret_cast<const float4*>(eattr + (size_t)e * 8);
    float4 a = p[0], b = p[1];
    __half2 h[4];
    h[0] = __floats2half2_rn(a.x, a.y); h[1] = __floats2half2_rn(a.z, a.w);
    h[2] = __floats2half2_rn(b.x, b.y); h[3] = __floats2half2_rn(b.z, b.w);
    *reinterpret_cast<float4*>(csr_ea + (size_t)pos * 8) = *reinterpret_cast<const float4*>(h);
}

// per-node mean of incoming (masked) raw edge attrs, from CSR (no atomics)
__global__ void loopmean_kernel(const int* __restrict__ csr_off, const __half* __restrict__ csr_ea,
                                float* __restrict__ loopm, float* __restrict__ selff) {
    int i = blockIdx.x * blockDim.x + threadIdx.x;   // N*8
    int n = i >> 3, j = i & 7;
    if (n >= N) return;
    int beg = csr_off[n], end = csr_off[n + 1];
    float s = 0.f;
    for (int idx = beg; idx < end; ++idx) s += __half2float(csr_ea[(size_t)idx * 8 + j]);
    int c = end - beg;
    loopm[n * 8 + j] = s / (float)(c > 1 ? c : 1);
    if (j == 0) selff[n] = (c > 0) ? 1.0f : 0.0f;
}

// [xl|xr] = x @ [Wl|Wr] + [bl|br] via f16 MFMA. Block=256 (4 waves), 16 nodes/block,
// wave w covers out-channels [w*64, w*64+64). A frags straight from row-major global.
__global__ __launch_bounds__(256) void transform_kernel(
        const __half* __restrict__ xh, const _Float16* __restrict__ wfrag,
        const float* __restrict__ bl, const float* __restrict__ br,
        __half* __restrict__ xl_h, __half* __restrict__ xr_h) {
    int w = threadIdx.x >> 6, lane = threadIdx.x & 63;
    int quad = lane >> 4, r16 = lane & 15;
    int m0 = blockIdx.x * 16;
    const _Float16* xrow = reinterpret_cast<const _Float16*>(xh) + (size_t)(m0 + r16) * D + quad * 8;
    half8 a[4];
    #pragma unroll
    for (int kt = 0; kt < 4; ++kt) a[kt] = *reinterpret_cast<const half8*>(xrow + kt * 32);
    f32x4 acc[4];
    #pragma unroll
    for (int nt = 0; nt < 4; ++nt) { f32x4 z = {0.f, 0.f, 0.f, 0.f}; acc[nt] = z; }
    #pragma unroll
    for (int nt = 0; nt < 4; ++nt) {
        int ntile = w * 4 + nt;
        #pragma unroll
        for (int kt = 0; kt < 4; ++kt) {
            half8 b = *reinterpret_cast<const half8*>(
                wfrag + ((size_t)(kt * 16 + ntile) * 64 + lane) * 8);
            acc[nt] = __builtin_amdgcn_mfma_f32_16x16x32_f16(a[kt], b, acc[nt], 0, 0, 0);
        }
    }
    #pragma unroll
    for (int nt = 0; nt < 4; ++nt) {
        int n = (w * 4 + nt) * 16 + r16;
        float bias = (n < 128) ? bl[n] : br[n - 128];
        #pragma unroll
        for (int r = 0; r < 4; ++r) {
            int node = m0 + quad * 4 + r;
            float v = acc[nt][r] + bias;
            if (n < 128) xl_h[(size_t)node * D + n] = __float2half_rn(v);
            else         xr_h[(size_t)node * D + (n - 128)] = __float2half_rn(v);
        }
    }
}

__device__ __forceinline__ void load8h(const __half* p, float o[8]) {
    float4 v = *reinterpret_cast<const float4*>(p);
    const __half2* h = reinterpret_cast<const __half2*>(&v);
    #pragma unroll
    for (int k = 0; k < 4; ++k) {
        float2 f = __half22float2(h[k]);
        o[2 * k] = f.x; o[2 * k + 1] = f.y;
    }
}

// One wave per node (2 nodes / 128-block). Thread = 2 channels. Online segment-softmax;
// edge loop unrolled x4 for gather latency hiding.
__global__ __launch_bounds__(128) void aggregate_kernel(
        const __half* __restrict__ xl_h, const __half* __restrict__ xr_h,
        const float* __restrict__ loopm, const float* __restrict__ selff,
        const int* __restrict__ csr_off, const int* __restrict__ csr_src,
        const __half* __restrict__ csr_ea,
        const float* __restrict__ Mfold, const float* __restrict__ cfold,
        const float* __restrict__ att, const float* __restrict__ gbias,
        const float* __restrict__ bn_gamma, const float* __restrict__ bn_beta,
        __half* __restrict__ xout) {
    int n = blockIdx.x * 2 + (threadIdx.x >> 6);
    int t = threadIdx.x & 63;        // lane in wave
    int c0 = t * 2;                  // channels c0, c0+1; head = t>>3 (8 lanes/head)
    float att0 = att[c0], att1 = att[c0 + 1];
    float M0[8], M1[8];
    #pragma unroll
    for (int j = 0; j < 8; ++j) { M0[j] = Mfold[j * D + c0]; M1[j] = Mfold[j * D + c0 + 1]; }
    float cf0 = cfold[c0], cf1 = cfold[c0 + 1];
    float2 xrv = __half22float2(*reinterpret_cast<const __half2*>(xr_h + (size_t)n * D + c0));
    float2 xlv = __half22float2(*reinterpret_cast<const __half2*>(xl_h + (size_t)n * D + c0));

    // self loop (edge attr = per-node mean of incoming raw attrs)
    float la[8];
    {
        const float4* p = reinterpret_cast<const float4*>(loopm + (size_t)n * 8);
        float4 a = p[0], b = p[1];
        la[0] = a.x; la[1] = a.y; la[2] = a.z; la[3] = a.w;
        la[4] = b.x; la[5] = b.y; la[6] = b.z; la[7] = b.w;
    }
    float sf = selff[n];
    float ep0 = cf0 * sf, ep1 = cf1 * sf;
    #pragma unroll
    for (int j = 0; j < 8; ++j) { ep0 += la[j] * M0[j]; ep1 += la[j] * M1[j]; }
    float z0 = xlv.x + xrv.x + ep0; z0 = z0 > 0.f ? z0 : 0.2f * z0;
    float z1 = xlv.y + xrv.y + ep1; z1 = z1 > 0.f ? z1 : 0.2f * z1;
    float lg = z0 * att0 + z1 * att1;
    lg += __shfl_xor(lg, 1); lg += __shfl_xor(lg, 2); lg += __shfl_xor(lg, 4);
    float m = lg, denom = 1.0f, acc0 = xlv.x, acc1 = xlv.y;

    int beg = csr_off[n], end = csr_off[n + 1];
    int idx = beg;
    for (; idx + 4 <= end; idx += 4) {
        int s0 = csr_src[idx], s1 = csr_src[idx + 1], s2 = csr_src[idx + 2], s3 = csr_src[idx + 3];
        __half2 g0 = *reinterpret_cast<const __half2*>(xl_h + (size_t)s0 * D + c0);
        __half2 g1 = *reinterpret_cast<const __half2*>(xl_h + (size_t)s1 * D + c0);
        __half2 g2 = *reinterpret_cast<const __half2*>(xl_h + (size_t)s2 * D + c0);
        __half2 g3 = *reinterpret_cast<const __half2*>(xl_h + (size_t)s3 * D + c0);
        float ea[4][8];
        load8h(csr_ea + (size_t)idx * 8,      ea[0]);
        load8h(csr_ea + (size_t)idx * 8 + 8,  ea[1]);
        load8h(csr_ea + (size_t)idx * 8 + 16, ea[2]);
        load8h(csr_ea + (size_t)idx * 8 + 24, ea[3]);
        float e0[4], e1[4];
        #pragma unroll
        for (int k = 0; k < 4; ++k) {
            float a0 = cf0, a1 = cf1;
            #pragma unroll
            for (int j = 0; j < 8; ++j) { a0 += ea[k][j] * M0[j]; a1 += ea[k][j] * M1[j]; }
            e0[k] = a0; e1[k] = a1;
        }
        float2 x0 = __half22float2(g0), x1 = __half22float2(g1);
        float2 x2 = __half22float2(g2), x3 = __half22float2(g3);
        float l0, l1, l2, l3;
        {
            float za = x0.x + xrv.x + e0[0]; za = za > 0.f ? za : 0.2f * za;
            float zb = x0.y + xrv.y + e1[0]; zb = zb > 0.f ? zb : 0.2f * zb;
            l0 = za * att0 + zb * att1;
            za = x1.x + xrv.x + e0[1]; za = za > 0.f ? za : 0.2f * za;
            zb = x1.y + xrv.y + e1[1]; zb = zb > 0.f ? zb : 0.2f * zb;
            l1 = za * att0 + zb * att1;
            za = x2.x + xrv.x + e0[2]; za = za > 0.f ? za : 0.2f * za;
            zb = x2.y + xrv.y + e1[2]; zb = zb > 0.f ? zb : 0.2f * zb;
            l2 = za * att0 + zb * att1;
            za = x3.x + xrv.x + e0[3]; za = za > 0.f ? za : 0.2f * za;
            zb = x3.y + xrv.y + e1[3]; zb = zb > 0.f ? zb : 0.2f * zb;
            l3 = za * att0 + zb * att1;
        }
        l0 += __shfl_xor(l0, 1); l0 += __shfl_xor(l0, 2); l0 += __shfl_xor(l0, 4);
        l1 += __shfl_xor(l1, 1); l1 += __shfl_xor(l1, 2); l1 += __shfl_xor(l1, 4);
        l2 += __shfl_xor(l2, 1); l2 += __shfl_xor(l2, 2); l2 += __shfl_xor(l2, 4);
        l3 += __shfl_xor(l3, 1); l3 += __shfl_xor(l3, 2); l3 += __shfl_xor(l3, 4);
        float nm = fmaxf(fmaxf(m, fmaxf(l0, l1)), fmaxf(l2, l3));
        float wo = __expf(m - nm);
        float w0 = __expf(l0 - nm), w1 = __expf(l1 - nm);
        float w2 = __expf(l2 - nm), w3 = __expf(l3 - nm);
        denom = denom * wo + (w0 + w1) + (w2 + w3);
        acc0 = acc0 * wo + w0 * x0.x + w1 * x1.x + w2 * x2.x + w3 * x3.x;
        acc1 = acc1 * wo + w0 * x0.y + w1 * x1.y + w2 * x2.y + w3 * x3.y;
        m = nm;
    }
    for (; idx < end; ++idx) {
        int s0 = csr_src[idx];
        __half2 g0 = *reinterpret_cast<const __half2*>(xl_h + (size_t)s0 * D + c0);
        float ea0[8];
        load8h(csr_ea + (size_t)idx * 8, ea0);
        float e00 = cf0, e01 = cf1;
        #pragma unroll
        for (int j = 0; j < 8; ++j) { e00 += ea0[j] * M0[j]; e01 += ea0[j] * M1[j]; }
        float2 x0 = __half22float2(g0);
        float za = x0.x + xrv.x + e00; za = za > 0.f ? za : 0.2f * za;
        float zb = x0.y + xrv.y + e01; zb = zb > 0.f ? zb : 0.2f * zb;
        float l0 = za * att0 + zb * att1;
        l0 += __shfl_xor(l0, 1); l0 += __shfl_xor(l0, 2); l0 += __shfl_xor(l0, 4);
        float nm = fmaxf(m, l0);
        float wo = __expf(m - nm), w0 = __expf(l0 - nm);
        denom = denom * wo + w0;
        acc0 = acc0 * wo + w0 * x0.x;
        acc1 = acc1 * wo + w0 * x0.y;
        m = nm;
    }
    float inv = 1.0f / denom;
    float h0 = acc0 * inv + gbias[c0];
    float h1 = acc1 * inv + gbias[c0 + 1];
    h0 = bn_gamma[c0] * h0 * 0.999995000037499813f + bn_beta[c0];
    h1 = bn_gamma[c0 + 1] * h1 * 0.999995000037499813f + bn_beta[c0 + 1];
    h0 = h0 > 0.f ? h0 : (__expf(h0) - 1.0f);
    h1 = h1 > 0.f ? h1 : (__expf(h1) - 1.0f);
    *reinterpret_cast<__half2*>(xout + (size_t)n * D + c0) = __floats2half2_rn(h0, h1);
}

__device__ __forceinline__ int lower_bound_dev(const int* a, int n, int v) {
    int lo = 0, hi = n;
    while (lo < hi) { int mid = (lo + hi) >> 1; if (a[mid] < v) lo = mid + 1; else hi = mid; }
    return lo;
}

// fused global mean pool + classifier head; batch is sorted -> per-graph ranges, no atomics
__global__ __launch_bounds__(128) void headpool_kernel(
        const __half* __restrict__ xh, const int* __restrict__ batch,
        const float* __restrict__ hW, const float* __restrict__ hb,
        float* __restrict__ out) {
    __shared__ float lds[128];
    int g = blockIdx.x, t = threadIdx.x;
    int lo = lower_bound_dev(batch, N, g);
    int hi = lower_bound_dev(batch, N, g + 1);
    float s = 0.f;
    for (int i = lo; i < hi; ++i) s += __half2float(xh[(size_t)i * D + t]);
    int c = hi - lo;
    lds[t] = s / (float)(c > 1 ? c : 1);
    __syncthreads();
    if (t < NC) {
        float p = hb[t];
        for (int cc = 0; cc < D; ++cc) p += lds[cc] * hW[cc * NC + t];
        out[g * NC + t] = p;
    }
}

extern "C" void kernel_launch(void* const* d_in, const int* in_sizes, int n_in,
                              void* d_out, int out_size, void* d_ws, size_t ws_size,
                              hipStream_t stream) {
    const int*   x_nodes   = (const int*)  d_in[0];
    const int*   edge_src  = (const int*)  d_in[1];
    const int*   edge_dst  = (const int*)  d_in[2];
    const float* edge_attr = (const float*)d_in[3];
    const int*   batch     = (const int*)  d_in[4];
    const float* node_emb  = (const float*)d_in[5];
    const float* edge_W    = (const float*)d_in[6];
    const float* edge_b    = (const float*)d_in[7];
    const float* Wl        = (const float*)d_in[8];
    const float* bl        = (const float*)d_in[9];
    const float* Wr        = (const float*)d_in[10];
    const float* br        = (const float*)d_in[11];
    const float* We        = (const float*)d_in[12];
    const float* att       = (const float*)d_in[13];
    const float* gbias     = (const float*)d_in[14];
    const float* bn_gamma  = (const float*)d_in[15];
    const float* bn_beta   = (const float*)d_in[16];
    const float* head_W    = (const float*)d_in[17];
    const float* head_b    = (const float*)d_in[18];
    float* out = (float*)d_out;

    float* ws = (float*)d_ws;
    int*    cnt      = (int*)(ws + O_CNT);
    int*    cursor   = (int*)(ws + O_CURSOR);
    int*    csr_off  = (int*)(ws + O_CSROFF);
    int*    bsum     = (int*)(ws + O_BSUM);
    int*    csr_src  = (int*)(ws + O_CSRSRC);
    __half* csr_ea   = (__half*)(ws + O_CSREA);
    float*  Mfold    = ws + O_MFOLD;
    float*  cfold    = ws + O_CFOLD;
    float*  loopm    = ws + O_LOOPM;
    float*  selff    = ws + O_SELFF;
    _Float16* wfrag  = (_Float16*)(ws + O_WFRAG);
    __half* xh   = (__half*)(ws + O_XH);
    __half* xl_h = (__half*)(ws + O_XLH);
    __half* xr_h = (__half*)(ws + O_XRH);

    // 1) zero cnt + cursor
    zero_kernel<<<((int)ZERO_END + 255) / 256, 256, 0, stream>>>(ws, (int)ZERO_END);
    // 2) node embedding (fp16)
    embed_kernel<<<(N * D + 255) / 256, 256, 0, stream>>>(x_nodes, node_emb, xh);
    // 3) folded edge transforms (f32)
    fold_kernel<<<L, D, 0, stream>>>(edge_W, edge_b, We, Mfold, cfold);
    // 4) fragment-ordered fp16 weights
    wcvt_kernel<<<(L * 32768 + 255) / 256, 256, 0, stream>>>(Wl, Wr, wfrag);
    // 5) per-dst degree
    edge_cnt_kernel<<<(E + 255) / 256, 256, 0, stream>>>(edge_src, edge_dst, cnt);
    // 6) exclusive scan -> csr_off
    {
        int nb = (N + 1023) / 1024;   // 49
        scan1_kernel<<<nb, 256, 0, stream>>>(cnt, csr_off + 1, bsum);
        scan2_kernel<<<1, 64, 0, stream>>>(bsum, nb);
        scan3_kernel<<<(N + 255) / 256, 256, 0, stream>>>(csr_off, bsum);
    }
    // 7) CSR scatter (src + fp16 edge attrs inline)
    csr_fill_kernel<<<(E + 255) / 256, 256, 0, stream>>>(edge_src, edge_dst, edge_attr,
                                                         csr_off, cursor, csr_src, csr_ea);
    // 8) per-node mean edge attr + self-loop flag (no atomics)
    loopmean_kernel<<<(N * 8 + 255) / 256, 256, 0, stream>>>(csr_off, csr_ea, loopm, selff);
    // 9) GAT layers
    for (int l = 0; l < L; ++l) {
        transform_kernel<<<N / 16, 256, 0, stream>>>(
            xh, wfrag + (size_t)l * 32768, bl + l * D, br + l * D, xl_h, xr_h);
        aggregate_kernel<<<N / 2, 128, 0, stream>>>(
            xl_h, xr_h, loopm, selff, csr_off, csr_src, csr_ea,
            Mfold + (size_t)l * EF * D, cfold + l * D, att + l * D, gbias + l * D,
            bn_gamma + l * D, bn_beta + l * D, xh);
    }
    // 10) fused mean-pool + head
    headpool_kernel<<<G, 128, 0, stream>>>(xh, batch, head_W, head_b, out);

    (void)in_sizes; (void)n_in; (void)out_size; (void)ws_size;
}

// Round 4
// 582.371 us; speedup vs baseline: 2.6549x; 1.2364x over previous
//
#include <hip/hip_runtime.h>
#include <hip/hip_fp16.h>
#include <math.h>

static constexpr int N  = 50000;
static constexpr int E  = 800000;
static constexpr int G  = 512;
static constexpr int D  = 128;
static constexpr int EF = 8;
static constexpr int EE = 64;
static constexpr int L  = 4;
static constexpr int NC = 10;

typedef _Float16 half8 __attribute__((ext_vector_type(8)));
typedef _Float16 h2v  __attribute__((ext_vector_type(2)));
typedef float f32x4 __attribute__((ext_vector_type(4)));

union H4 { float4 f4; h2v h[4]; };

#if __has_builtin(__builtin_amdgcn_fdot2)
#define FDOT2(a, b, c) __builtin_amdgcn_fdot2((a), (b), (c), false)
#else
#define FDOT2(a, b, c) ((float)(a)[0]*(float)(b)[0] + (float)(a)[1]*(float)(b)[1] + (c))
#endif

static constexpr size_t pad64(size_t w){ return (w + 63) & ~size_t(63); }
// workspace layout in 4-byte words; [0, ZERO_END) is zero-initialized by prep
static constexpr size_t O_CNT     = 0;                               // N ints
static constexpr size_t O_CURSOR  = O_CNT + pad64(N);                // N ints
static constexpr size_t ZERO_END  = O_CURSOR + pad64(N);
static constexpr size_t O_CSROFF  = ZERO_END;                        // N+1 ints
static constexpr size_t O_BSUM    = O_CSROFF + pad64(N+1);           // 64 ints
static constexpr size_t O_CSRSRC  = O_BSUM + 64;                     // E ints
static constexpr size_t O_CSREA   = O_CSRSRC + pad64(E);             // E*8 halfs = E*4 words
static constexpr size_t O_MH      = O_CSREA + pad64((size_t)E*4);    // L*D*8 halfs = L*512 words
static constexpr size_t O_CFOLD   = O_MH + pad64((size_t)L*512);     // L*D f32
static constexpr size_t O_LOOPM   = O_CFOLD + pad64(L*D);            // N*8 f32
static constexpr size_t O_SELFF   = O_LOOPM + pad64((size_t)N*8);    // N f32
static constexpr size_t O_WFRAG   = O_SELFF + pad64(N);              // L*32768 halfs
static constexpr size_t O_XH      = O_WFRAG + pad64((size_t)L*16384);// N*D halfs
static constexpr size_t O_XLH     = O_XH  + pad64((size_t)N*64);
static constexpr size_t O_XRH     = O_XLH + pad64((size_t)N*64);

// prep grid partition (256-thread blocks)
static constexpr int PB_EMB  = (N * D) / 256;                 // 25000
static constexpr int PB_ZERO = ((int)ZERO_END + 255) / 256;   // zero cnt+cursor
static constexpr int PB_WCVT = (L * 32768) / 256;             // 512
static constexpr int PB_FOLD = L;                             // 4
static constexpr int PB_TOTAL = PB_EMB + PB_ZERO + PB_WCVT + PB_FOLD;

// fused: embed (fp16) | zero | wcvt (fragment-ordered weights) | fold (edge proj fold, fp16)
__global__ __launch_bounds__(256) void prep_kernel(
        const int* __restrict__ xn, const float* __restrict__ emb, __half* __restrict__ xh,
        float* __restrict__ zbase,
        const float* __restrict__ Wl, const float* __restrict__ Wr, _Float16* __restrict__ wfrag,
        const float* __restrict__ edge_W, const float* __restrict__ edge_b,
        const float* __restrict__ We, _Float16* __restrict__ Mh, float* __restrict__ cfold) {
    int bid = blockIdx.x, t = threadIdx.x;
    if (bid < PB_EMB) {
        int i = bid * 256 + t;                     // N*D
        int n = i >> 7, c = i & 127;
        xh[i] = __float2half_rn(emb[xn[n] * D + c]);
    } else if (bid < PB_EMB + PB_ZERO) {
        int i = (bid - PB_EMB) * 256 + t;
        if (i < (int)ZERO_END) zbase[i] = 0.0f;
    } else if (bid < PB_EMB + PB_ZERO + PB_WCVT) {
        int i = (bid - PB_EMB - PB_ZERO) * 256 + t; // L*32768
        int j    = i & 7;
        int lane = (i >> 3) & 63;
        int nt   = (i >> 9) & 15;
        int kt   = (i >> 13) & 3;
        int l    = i >> 15;
        int k = kt * 32 + (lane >> 4) * 8 + j;
        int n = nt * 16 + (lane & 15);
        float v = (n < 128) ? Wl[((size_t)l * D + k) * D + n]
                            : Wr[((size_t)l * D + k) * D + (n - 128)];
        wfrag[i] = (_Float16)v;
    } else {
        int l = bid - PB_EMB - PB_ZERO - PB_WCVT;  // 4 blocks
        if (t >= 128) return;
        const float* Wel = We + (size_t)l * EE * D;
        for (int j = 0; j < EF; ++j) {
            float s = 0.f;
            for (int k = 0; k < EE; ++k) s += edge_W[j * EE + k] * Wel[k * D + t];
            Mh[((size_t)l * D + t) * 8 + j] = (_Float16)s;   // [l][c][j]
        }
        float s = 0.f;
        for (int k = 0; k < EE; ++k) s += edge_b[k] * Wel[k * D + t];
        cfold[l * D + t] = s;
    }
}

__global__ void edge_cnt_kernel(const int* __restrict__ src, const int* __restrict__ dst,
                                int* __restrict__ cnt) {
    int e = blockIdx.x * blockDim.x + threadIdx.x;
    if (e >= E) return;
    if (src[e] != dst[e]) atomicAdd(&cnt[dst[e]], 1);
}

// scan over cnt[N] -> csr_off[1+i] = inclusive prefix within block; bsum[b] = block total
__global__ void scan1_kernel(const int* __restrict__ cnt, int* __restrict__ out /*=csr_off+1*/,
                             int* __restrict__ bsum) {
    __shared__ int lds[256];
    int b = blockIdx.x, t = threadIdx.x;
    int base = b * 1024 + t * 4;
    int v[4]; int s = 0;
    #pragma unroll
    for (int k = 0; k < 4; ++k) { int idx = base + k; v[k] = (idx < N) ? cnt[idx] : 0; s += v[k]; }
    lds[t] = s; __syncthreads();
    for (int off = 1; off < 256; off <<= 1) {
        int add = (t >= off) ? lds[t - off] : 0;
        __syncthreads();
        lds[t] += add;
        __syncthreads();
    }
    int run = (t > 0) ? lds[t - 1] : 0;
    #pragma unroll
    for (int k = 0; k < 4; ++k) { run += v[k]; int idx = base + k; if (idx < N) out[idx] = run; }
    if (t == 255) bsum[b] = lds[255];
}

// add cross-block prefix (49 entries, L2-hot, recomputed per thread) -> csr_off exclusive
__global__ void scan3_kernel(int* __restrict__ csr_off, const int* __restrict__ bsum) {
    int i = blockIdx.x * blockDim.x + threadIdx.x;
    if (i == 0) csr_off[0] = 0;
    if (i >= N) return;
    int b = i >> 10;
    int add = 0;
    for (int k = 0; k < b; ++k) add += bsum[k];
    csr_off[1 + i] += add;
}

// CSR fill with src id and fp16 edge attr inlined
__global__ void csr_fill_kernel(const int* __restrict__ src, const int* __restrict__ dst,
                                const float* __restrict__ eattr,
                                const int* __restrict__ csr_off, int* __restrict__ cursor,
                                int* __restrict__ csr_src, __half* __restrict__ csr_ea) {
    int e = blockIdx.x * blockDim.x + threadIdx.x;
    if (e >= E) return;
    int s = src[e], d = dst[e];
    if (s == d) return;
    int pos = csr_off[d] + atomicAdd(&cursor[d], 1);
    csr_src[pos] = s;
    const float4* p = reinterpret_cast<const float4*>(eattr + (size_t)e * 8);
    float4 a = p[0], b = p[1];
    __half2 h[4];
    h[0] = __floats2half2_rn(a.x, a.y); h[1] = __floats2half2_rn(a.z, a.w);
    h[2] = __floats2half2_rn(b.x, b.y); h[3] = __floats2half2_rn(b.z, b.w);
    *reinterpret_cast<float4*>(csr_ea + (size_t)pos * 8) = *reinterpret_cast<const float4*>(h);
}

// per-node mean of incoming (masked) raw edge attrs, from CSR (no atomics)
__global__ void loopmean_kernel(const int* __restrict__ csr_off, const __half* __restrict__ csr_ea,
                                float* __restrict__ loopm, float* __restrict__ selff) {
    int i = blockIdx.x * blockDim.x + threadIdx.x;   // N*8
    int n = i >> 3, j = i & 7;
    if (n >= N) return;
    int beg = csr_off[n], end = csr_off[n + 1];
    float s = 0.f;
    for (int idx = beg; idx < end; ++idx) s += __half2float(csr_ea[(size_t)idx * 8 + j]);
    int c = end - beg;
    loopm[n * 8 + j] = s / (float)(c > 1 ? c : 1);
    if (j == 0) selff[n] = (c > 0) ? 1.0f : 0.0f;
}

// [xl|xr] = x @ [Wl|Wr] + [bl|br] via f16 MFMA. Block=256 (4 waves), 16 nodes/block.
__global__ __launch_bounds__(256) void transform_kernel(
        const __half* __restrict__ xh, const _Float16* __restrict__ wfrag,
        const float* __restrict__ bl, const float* __restrict__ br,
        __half* __restrict__ xl_h, __half* __restrict__ xr_h) {
    int w = threadIdx.x >> 6, lane = threadIdx.x & 63;
    int quad = lane >> 4, r16 = lane & 15;
    int m0 = blockIdx.x * 16;
    const _Float16* xrow = reinterpret_cast<const _Float16*>(xh) + (size_t)(m0 + r16) * D + quad * 8;
    half8 a[4];
    #pragma unroll
    for (int kt = 0; kt < 4; ++kt) a[kt] = *reinterpret_cast<const half8*>(xrow + kt * 32);
    f32x4 acc[4];
    #pragma unroll
    for (int nt = 0; nt < 4; ++nt) { f32x4 z = {0.f, 0.f, 0.f, 0.f}; acc[nt] = z; }
    #pragma unroll
    for (int nt = 0; nt < 4; ++nt) {
        int ntile = w * 4 + nt;
        #pragma unroll
        for (int kt = 0; kt < 4; ++kt) {
            half8 b = *reinterpret_cast<const half8*>(
                wfrag + ((size_t)(kt * 16 + ntile) * 64 + lane) * 8);
            acc[nt] = __builtin_amdgcn_mfma_f32_16x16x32_f16(a[kt], b, acc[nt], 0, 0, 0);
        }
    }
    #pragma unroll
    for (int nt = 0; nt < 4; ++nt) {
        int n = (w * 4 + nt) * 16 + r16;
        float bias = (n < 128) ? bl[n] : br[n - 128];
        #pragma unroll
        for (int r = 0; r < 4; ++r) {
            int node = m0 + quad * 4 + r;
            float v = acc[nt][r] + bias;
            if (n < 128) xl_h[(size_t)node * D + n] = __float2half_rn(v);
            else         xr_h[(size_t)node * D + (n - 128)] = __float2half_rn(v);
        }
    }
}

// One wave per node (2 nodes / 128-block). Thread = 2 channels. Online segment-softmax.
// Edge projection via v_dot2_f32_f16 (fp16 mul, f32 accumulate), edge loop unrolled x4.
__global__ __launch_bounds__(128) void aggregate_kernel(
        const __half* __restrict__ xl_h, const __half* __restrict__ xr_h,
        const float* __restrict__ loopm, const float* __restrict__ selff,
        const int* __restrict__ csr_off, const int* __restrict__ csr_src,
        const __half* __restrict__ csr_ea,
        const _Float16* __restrict__ Mh, const float* __restrict__ cfold,
        const float* __restrict__ att, const float* __restrict__ gbias,
        const float* __restrict__ bn_gamma, const float* __restrict__ bn_beta,
        __half* __restrict__ xout) {
    int n = blockIdx.x * 2 + (threadIdx.x >> 6);
    int t = threadIdx.x & 63;        // lane in wave
    int c0 = t * 2;                  // channels c0, c0+1; head = t>>3 (8 lanes/head)
    float att0 = att[c0], att1 = att[c0 + 1];
    H4 m0u, m1u;
    m0u.f4 = *reinterpret_cast<const float4*>(Mh + (size_t)c0 * 8);
    m1u.f4 = *reinterpret_cast<const float4*>(Mh + (size_t)(c0 + 1) * 8);
    float cf0 = cfold[c0], cf1 = cfold[c0 + 1];
    float2 xrv = __half22float2(*reinterpret_cast<const __half2*>(xr_h + (size_t)n * D + c0));
    float2 xlv = __half22float2(*reinterpret_cast<const __half2*>(xl_h + (size_t)n * D + c0));

    // self loop (edge attr = per-node mean of incoming raw attrs)
    H4 lau;
    {
        const float4* p = reinterpret_cast<const float4*>(loopm + (size_t)n * 8);
        float4 a = p[0], b = p[1];
        lau.h[0] = h2v{(_Float16)a.x, (_Float16)a.y};
        lau.h[1] = h2v{(_Float16)a.z, (_Float16)a.w};
        lau.h[2] = h2v{(_Float16)b.x, (_Float16)b.y};
        lau.h[3] = h2v{(_Float16)b.z, (_Float16)b.w};
    }
    float sf = selff[n];
    float ep0 = cf0 * sf, ep1 = cf1 * sf;
    #pragma unroll
    for (int k = 0; k < 4; ++k) { ep0 = FDOT2(lau.h[k], m0u.h[k], ep0); ep1 = FDOT2(lau.h[k], m1u.h[k], ep1); }
    float z0 = xlv.x + xrv.x + ep0; z0 = fmaxf(z0, 0.2f * z0);
    float z1 = xlv.y + xrv.y + ep1; z1 = fmaxf(z1, 0.2f * z1);
    float lg = z0 * att0 + z1 * att1;
    lg += __shfl_xor(lg, 1); lg += __shfl_xor(lg, 2); lg += __shfl_xor(lg, 4);
    float m = lg, denom = 1.0f, acc0 = xlv.x, acc1 = xlv.y;

    int beg = csr_off[n], end = csr_off[n + 1];
    int idx = beg;
    for (; idx + 4 <= end; idx += 4) {
        int s0 = csr_src[idx], s1 = csr_src[idx + 1], s2 = csr_src[idx + 2], s3 = csr_src[idx + 3];
        __half2 g0 = *reinterpret_cast<const __half2*>(xl_h + (size_t)s0 * D + c0);
        __half2 g1 = *reinterpret_cast<const __half2*>(xl_h + (size_t)s1 * D + c0);
        __half2 g2 = *reinterpret_cast<const __half2*>(xl_h + (size_t)s2 * D + c0);
        __half2 g3 = *reinterpret_cast<const __half2*>(xl_h + (size_t)s3 * D + c0);
        H4 e0u, e1u, e2u, e3u;
        e0u.f4 = *reinterpret_cast<const float4*>(csr_ea + (size_t)idx * 8);
        e1u.f4 = *reinterpret_cast<const float4*>(csr_ea + (size_t)idx * 8 + 8);
        e2u.f4 = *reinterpret_cast<const float4*>(csr_ea + (size_t)idx * 8 + 16);
        e3u.f4 = *reinterpret_cast<const float4*>(csr_ea + (size_t)idx * 8 + 24);
        float p00 = cf0, p01 = cf1, p10 = cf0, p11 = cf1;
        float p20 = cf0, p21 = cf1, p30 = cf0, p31 = cf1;
        #pragma unroll
        for (int k = 0; k < 4; ++k) {
            p00 = FDOT2(e0u.h[k], m0u.h[k], p00); p01 = FDOT2(e0u.h[k], m1u.h[k], p01);
            p10 = FDOT2(e1u.h[k], m0u.h[k], p10); p11 = FDOT2(e1u.h[k], m1u.h[k], p11);
            p20 = FDOT2(e2u.h[k], m0u.h[k], p20); p21 = FDOT2(e2u.h[k], m1u.h[k], p21);
            p30 = FDOT2(e3u.h[k], m0u.h[k], p30); p31 = FDOT2(e3u.h[k], m1u.h[k], p31);
        }
        float2 x0 = __half22float2(g0), x1 = __half22float2(g1);
        float2 x2 = __half22float2(g2), x3 = __half22float2(g3);
        float za, zb, l0, l1, l2, l3;
        za = x0.x + xrv.x + p00; za = fmaxf(za, 0.2f * za);
        zb = x0.y + xrv.y + p01; zb = fmaxf(zb, 0.2f * zb);
        l0 = za * att0 + zb * att1;
        za = x1.x + xrv.x + p10; za = fmaxf(za, 0.2f * za);
        zb = x1.y + xrv.y + p11; zb = fmaxf(zb, 0.2f * zb);
        l1 = za * att0 + zb * att1;
        za = x2.x + xrv.x + p20; za = fmaxf(za, 0.2f * za);
        zb = x2.y + xrv.y + p21; zb = fmaxf(zb, 0.2f * zb);
        l2 = za * att0 + zb * att1;
        za = x3.x + xrv.x + p30; za = fmaxf(za, 0.2f * za);
        zb = x3.y + xrv.y + p31; zb = fmaxf(zb, 0.2f * zb);
        l3 = za * att0 + zb * att1;
        l0 += __shfl_xor(l0, 1); l0 += __shfl_xor(l0, 2); l0 += __shfl_xor(l0, 4);
        l1 += __shfl_xor(l1, 1); l1 += __shfl_xor(l1, 2); l1 += __shfl_xor(l1, 4);
        l2 += __shfl_xor(l2, 1); l2 += __shfl_xor(l2, 2); l2 += __shfl_xor(l2, 4);
        l3 += __shfl_xor(l3, 1); l3 += __shfl_xor(l3, 2); l3 += __shfl_xor(l3, 4);
        float nm = fmaxf(fmaxf(m, fmaxf(l0, l1)), fmaxf(l2, l3));
        float wo = __expf(m - nm);
        float w0 = __expf(l0 - nm), w1 = __expf(l1 - nm);
        float w2 = __expf(l2 - nm), w3 = __expf(l3 - nm);
        denom = denom * wo + (w0 + w1) + (w2 + w3);
        acc0 = acc0 * wo + w0 * x0.x + w1 * x1.x + w2 * x2.x + w3 * x3.x;
        acc1 = acc1 * wo + w0 * x0.y + w1 * x1.y + w2 * x2.y + w3 * x3.y;
        m = nm;
    }
    for (; idx < end; ++idx) {
        int s0 = csr_src[idx];
        __half2 g0 = *reinterpret_cast<const __half2*>(xl_h + (size_t)s0 * D + c0);
        H4 e0u;
        e0u.f4 = *reinterpret_cast<const float4*>(csr_ea + (size_t)idx * 8);
        float p00 = cf0, p01 = cf1;
        #pragma unroll
        for (int k = 0; k < 4; ++k) { p00 = FDOT2(e0u.h[k], m0u.h[k], p00); p01 = FDOT2(e0u.h[k], m1u.h[k], p01); }
        float2 x0 = __half22float2(g0);
        float za = x0.x + xrv.x + p00; za = fmaxf(za, 0.2f * za);
        float zb = x0.y + xrv.y + p01; zb = fmaxf(zb, 0.2f * zb);
        float l0 = za * att0 + zb * att1;
        l0 += __shfl_xor(l0, 1); l0 += __shfl_xor(l0, 2); l0 += __shfl_xor(l0, 4);
        float nm = fmaxf(m, l0);
        float wo = __expf(m - nm), w0 = __expf(l0 - nm);
        denom = denom * wo + w0;
        acc0 = acc0 * wo + w0 * x0.x;
        acc1 = acc1 * wo + w0 * x0.y;
        m = nm;
    }
    float inv = 1.0f / denom;
    float h0 = acc0 * inv + gbias[c0];
    float h1 = acc1 * inv + gbias[c0 + 1];
    h0 = bn_gamma[c0] * h0 * 0.999995000037499813f + bn_beta[c0];
    h1 = bn_gamma[c0 + 1] * h1 * 0.999995000037499813f + bn_beta[c0 + 1];
    h0 = h0 > 0.f ? h0 : (__expf(h0) - 1.0f);
    h1 = h1 > 0.f ? h1 : (__expf(h1) - 1.0f);
    *reinterpret_cast<__half2*>(xout + (size_t)n * D + c0) = __floats2half2_rn(h0, h1);
}

__device__ __forceinline__ int lower_bound_dev(const int* a, int n, int v) {
    int lo = 0, hi = n;
    while (lo < hi) { int mid = (lo + hi) >> 1; if (a[mid] < v) lo = mid + 1; else hi = mid; }
    return lo;
}

// fused global mean pool + classifier head; batch sorted -> per-graph ranges, no atomics
__global__ __launch_bounds__(128) void headpool_kernel(
        const __half* __restrict__ xh, const int* __restrict__ batch,
        const float* __restrict__ hW, const float* __restrict__ hb,
        float* __restrict__ out) {
    __shared__ float lds[128];
    int g = blockIdx.x, t = threadIdx.x;
    int lo = lower_bound_dev(batch, N, g);
    int hi = lower_bound_dev(batch, N, g + 1);
    float s = 0.f;
    #pragma unroll 4
    for (int i = lo; i < hi; ++i) s += __half2float(xh[(size_t)i * D + t]);
    int c = hi - lo;
    lds[t] = s / (float)(c > 1 ? c : 1);
    __syncthreads();
    if (t < NC) {
        float p = hb[t];
        #pragma unroll 8
        for (int cc = 0; cc < D; ++cc) p += lds[cc] * hW[cc * NC + t];
        out[g * NC + t] = p;
    }
}

extern "C" void kernel_launch(void* const* d_in, const int* in_sizes, int n_in,
                              void* d_out, int out_size, void* d_ws, size_t ws_size,
                              hipStream_t stream) {
    const int*   x_nodes   = (const int*)  d_in[0];
    const int*   edge_src  = (const int*)  d_in[1];
    const int*   edge_dst  = (const int*)  d_in[2];
    const float* edge_attr = (const float*)d_in[3];
    const int*   batch     = (const int*)  d_in[4];
    const float* node_emb  = (const float*)d_in[5];
    const float* edge_W    = (const float*)d_in[6];
    const float* edge_b    = (const float*)d_in[7];
    const float* Wl        = (const float*)d_in[8];
    const float* bl        = (const float*)d_in[9];
    const float* Wr        = (const float*)d_in[10];
    const float* br        = (const float*)d_in[11];
    const float* We        = (const float*)d_in[12];
    const float* att       = (const float*)d_in[13];
    const float* gbias     = (const float*)d_in[14];
    const float* bn_gamma  = (const float*)d_in[15];
    const float* bn_beta   = (const float*)d_in[16];
    const float* head_W    = (const float*)d_in[17];
    const float* head_b    = (const float*)d_in[18];
    float* out = (float*)d_out;

    float* ws = (float*)d_ws;
    int*    cnt      = (int*)(ws + O_CNT);
    int*    cursor   = (int*)(ws + O_CURSOR);
    int*    csr_off  = (int*)(ws + O_CSROFF);
    int*    bsum     = (int*)(ws + O_BSUM);
    int*    csr_src  = (int*)(ws + O_CSRSRC);
    __half* csr_ea   = (__half*)(ws + O_CSREA);
    _Float16* Mh     = (_Float16*)(ws + O_MH);
    float*  cfold    = ws + O_CFOLD;
    float*  loopm    = ws + O_LOOPM;
    float*  selff    = ws + O_SELFF;
    _Float16* wfrag  = (_Float16*)(ws + O_WFRAG);
    __half* xh   = (__half*)(ws + O_XH);
    __half* xl_h = (__half*)(ws + O_XLH);
    __half* xr_h = (__half*)(ws + O_XRH);

    // 1) fused prep: embed + zero + weight-fragment cvt + edge-proj fold
    prep_kernel<<<PB_TOTAL, 256, 0, stream>>>(x_nodes, node_emb, xh, ws,
                                              Wl, Wr, wfrag, edge_W, edge_b, We, Mh, cfold);
    // 2) per-dst degree
    edge_cnt_kernel<<<(E + 255) / 256, 256, 0, stream>>>(edge_src, edge_dst, cnt);
    // 3) exclusive scan -> csr_off (2 launches)
    {
        int nb = (N + 1023) / 1024;   // 49
        scan1_kernel<<<nb, 256, 0, stream>>>(cnt, csr_off + 1, bsum);
        scan3_kernel<<<(N + 255) / 256, 256, 0, stream>>>(csr_off, bsum);
    }
    // 4) CSR scatter (src + fp16 edge attrs inline)
    csr_fill_kernel<<<(E + 255) / 256, 256, 0, stream>>>(edge_src, edge_dst, edge_attr,
                                                         csr_off, cursor, csr_src, csr_ea);
    // 5) per-node mean edge attr + self-loop flag
    loopmean_kernel<<<(N * 8 + 255) / 256, 256, 0, stream>>>(csr_off, csr_ea, loopm, selff);
    // 6) GAT layers
    for (int l = 0; l < L; ++l) {
        transform_kernel<<<N / 16, 256, 0, stream>>>(
            xh, wfrag + (size_t)l * 32768, bl + l * D, br + l * D, xl_h, xr_h);
        aggregate_kernel<<<N / 2, 128, 0, stream>>>(
            xl_h, xr_h, loopm, selff, csr_off, csr_src, csr_ea,
            Mh + (size_t)l * D * 8, cfold + l * D, att + l * D, gbias + l * D,
            bn_gamma + l * D, bn_beta + l * D, xh);
    }
    // 7) fused mean-pool + head
    headpool_kernel<<<G, 128, 0, stream>>>(xh, batch, head_W, head_b, out);

    (void)in_sizes; (void)n_in; (void)out_size; (void)ws_size;
}

// Round 5
// 576.955 us; speedup vs baseline: 2.6798x; 1.0094x over previous
//
#include <hip/hip_runtime.h>
#include <hip/hip_fp16.h>
#include <math.h>

static constexpr int N  = 50000;
static constexpr int E  = 800000;
static constexpr int G  = 512;
static constexpr int D  = 128;
static constexpr int EF = 8;
static constexpr int EE = 64;
static constexpr int L  = 4;
static constexpr int NC = 10;

typedef _Float16 half8 __attribute__((ext_vector_type(8)));
typedef _Float16 h2v  __attribute__((ext_vector_type(2)));
typedef float f32x4 __attribute__((ext_vector_type(4)));

union H4 { float4 f4; h2v h[4]; };

#if __has_builtin(__builtin_amdgcn_fdot2)
#define FDOT2(a, b, c) __builtin_amdgcn_fdot2((a), (b), (c), false)
#else
#define FDOT2(a, b, c) ((float)(a)[0]*(float)(b)[0] + (float)(a)[1]*(float)(b)[1] + (c))
#endif

static constexpr size_t pad64(size_t w){ return (w + 63) & ~size_t(63); }
// workspace layout in 4-byte words; [0, ZERO_END) is zero-initialized by prep
static constexpr size_t O_CNT     = 0;                               // N ints
static constexpr size_t O_CURSOR  = O_CNT + pad64(N);                // N ints
static constexpr size_t ZERO_END  = O_CURSOR + pad64(N);
static constexpr size_t O_CSROFF  = ZERO_END;                        // N+1 ints
static constexpr size_t O_BSUM    = O_CSROFF + pad64(N+1);           // 64 ints
static constexpr size_t O_CSRSRC  = O_BSUM + 64;                     // E ints (row BYTE offsets)
static constexpr size_t O_CSREA   = O_CSRSRC + pad64(E);             // E*8 halfs = E*4 words
static constexpr size_t O_MH      = O_CSREA + pad64((size_t)E*4);    // L*D*8 halfs = L*512 words
static constexpr size_t O_CFOLD   = O_MH + pad64((size_t)L*512);     // L*D f32
static constexpr size_t O_LOOPM   = O_CFOLD + pad64(L*D);            // N*8 halfs = N*4 words
static constexpr size_t O_SELFF   = O_LOOPM + pad64((size_t)N*4);    // N f32
static constexpr size_t O_WFRAG   = O_SELFF + pad64(N);              // L*32768 halfs
static constexpr size_t O_XH      = O_WFRAG + pad64((size_t)L*16384);// N*D halfs
static constexpr size_t O_XLH     = O_XH  + pad64((size_t)N*64);
static constexpr size_t O_XRH     = O_XLH + pad64((size_t)N*64);

// prep grid partition (256-thread blocks)
static constexpr int PB_EMB  = (N * D) / 256;                 // 25000
static constexpr int PB_ZERO = ((int)ZERO_END + 255) / 256;   // zero cnt+cursor
static constexpr int PB_WCVT = (L * 32768) / 256;             // 512
static constexpr int PB_FOLD = L;                             // 4
static constexpr int PB_TOTAL = PB_EMB + PB_ZERO + PB_WCVT + PB_FOLD;

// fused: embed (fp16) | zero | wcvt (fragment-ordered weights) | fold (edge proj fold, fp16)
__global__ __launch_bounds__(256) void prep_kernel(
        const int* __restrict__ xn, const float* __restrict__ emb, __half* __restrict__ xh,
        float* __restrict__ zbase,
        const float* __restrict__ Wl, const float* __restrict__ Wr, _Float16* __restrict__ wfrag,
        const float* __restrict__ edge_W, const float* __restrict__ edge_b,
        const float* __restrict__ We, _Float16* __restrict__ Mh, float* __restrict__ cfold) {
    int bid = blockIdx.x, t = threadIdx.x;
    if (bid < PB_EMB) {
        int i = bid * 256 + t;                     // N*D
        int n = i >> 7, c = i & 127;
        xh[i] = __float2half_rn(emb[xn[n] * D + c]);
    } else if (bid < PB_EMB + PB_ZERO) {
        int i = (bid - PB_EMB) * 256 + t;
        if (i < (int)ZERO_END) zbase[i] = 0.0f;
    } else if (bid < PB_EMB + PB_ZERO + PB_WCVT) {
        int i = (bid - PB_EMB - PB_ZERO) * 256 + t; // L*32768
        int j    = i & 7;
        int lane = (i >> 3) & 63;
        int nt   = (i >> 9) & 15;
        int kt   = (i >> 13) & 3;
        int l    = i >> 15;
        int k = kt * 32 + (lane >> 4) * 8 + j;
        int n = nt * 16 + (lane & 15);
        float v = (n < 128) ? Wl[((size_t)l * D + k) * D + n]
                            : Wr[((size_t)l * D + k) * D + (n - 128)];
        wfrag[i] = (_Float16)v;
    } else {
        int l = bid - PB_EMB - PB_ZERO - PB_WCVT;  // 4 blocks
        if (t >= 128) return;
        const float* Wel = We + (size_t)l * EE * D;
        for (int j = 0; j < EF; ++j) {
            float s = 0.f;
            for (int k = 0; k < EE; ++k) s += edge_W[j * EE + k] * Wel[k * D + t];
            Mh[((size_t)l * D + t) * 8 + j] = (_Float16)s;   // [l][c][j]
        }
        float s = 0.f;
        for (int k = 0; k < EE; ++k) s += edge_b[k] * Wel[k * D + t];
        cfold[l * D + t] = s;
    }
}

__global__ void edge_cnt_kernel(const int* __restrict__ src, const int* __restrict__ dst,
                                int* __restrict__ cnt) {
    int e = blockIdx.x * blockDim.x + threadIdx.x;
    if (e >= E) return;
    if (src[e] != dst[e]) atomicAdd(&cnt[dst[e]], 1);
}

// scan over cnt[N] -> csr_off[1+i] = inclusive prefix within block; bsum[b] = block total
__global__ void scan1_kernel(const int* __restrict__ cnt, int* __restrict__ out /*=csr_off+1*/,
                             int* __restrict__ bsum) {
    __shared__ int lds[256];
    int b = blockIdx.x, t = threadIdx.x;
    int base = b * 1024 + t * 4;
    int v[4]; int s = 0;
    #pragma unroll
    for (int k = 0; k < 4; ++k) { int idx = base + k; v[k] = (idx < N) ? cnt[idx] : 0; s += v[k]; }
    lds[t] = s; __syncthreads();
    for (int off = 1; off < 256; off <<= 1) {
        int add = (t >= off) ? lds[t - off] : 0;
        __syncthreads();
        lds[t] += add;
        __syncthreads();
    }
    int run = (t > 0) ? lds[t - 1] : 0;
    #pragma unroll
    for (int k = 0; k < 4; ++k) { run += v[k]; int idx = base + k; if (idx < N) out[idx] = run; }
    if (t == 255) bsum[b] = lds[255];
}

// add cross-block prefix (49 entries, L2-hot) -> csr_off exclusive
__global__ void scan3_kernel(int* __restrict__ csr_off, const int* __restrict__ bsum) {
    int i = blockIdx.x * blockDim.x + threadIdx.x;
    if (i == 0) csr_off[0] = 0;
    if (i >= N) return;
    int b = i >> 10;
    int add = 0;
    for (int k = 0; k < b; ++k) add += bsum[k];
    csr_off[1 + i] += add;
}

// CSR fill: src stored as row BYTE offset into xl_h (s * D * 2); fp16 edge attr inlined
__global__ void csr_fill_kernel(const int* __restrict__ src, const int* __restrict__ dst,
                                const float* __restrict__ eattr,
                                const int* __restrict__ csr_off, int* __restrict__ cursor,
                                int* __restrict__ csr_src, __half* __restrict__ csr_ea) {
    int e = blockIdx.x * blockDim.x + threadIdx.x;
    if (e >= E) return;
    int s = src[e], d = dst[e];
    if (s == d) return;
    int pos = csr_off[d] + atomicAdd(&cursor[d], 1);
    csr_src[pos] = s << 8;   // byte offset of row s (128 ch * 2 B)
    const float4* p = reinterpret_cast<const float4*>(eattr + (size_t)e * 8);
    float4 a = p[0], b = p[1];
    __half2 h[4];
    h[0] = __floats2half2_rn(a.x, a.y); h[1] = __floats2half2_rn(a.z, a.w);
    h[2] = __floats2half2_rn(b.x, b.y); h[3] = __floats2half2_rn(b.z, b.w);
    *reinterpret_cast<float4*>(csr_ea + (size_t)pos * 8) = *reinterpret_cast<const float4*>(h);
}

// per-node mean of incoming (masked) raw edge attrs, from CSR (no atomics); fp16 out
__global__ void loopmean_kernel(const int* __restrict__ csr_off, const __half* __restrict__ csr_ea,
                                __half* __restrict__ loopm, float* __restrict__ selff) {
    int i = blockIdx.x * blockDim.x + threadIdx.x;   // N*8
    int n = i >> 3, j = i & 7;
    if (n >= N) return;
    int beg = csr_off[n], end = csr_off[n + 1];
    float s = 0.f;
    for (int idx = beg; idx < end; ++idx) s += __half2float(csr_ea[(size_t)idx * 8 + j]);
    int c = end - beg;
    loopm[(size_t)n * 8 + j] = __float2half_rn(s / (float)(c > 1 ? c : 1));
    if (j == 0) selff[n] = (c > 0) ? 1.0f : 0.0f;
}

// [xl|xr] = x @ [Wl|Wr] + [bl|br] via f16 MFMA. Block=256 (4 waves), 16 nodes/block.
__global__ __launch_bounds__(256) void transform_kernel(
        const __half* __restrict__ xh, const _Float16* __restrict__ wfrag,
        const float* __restrict__ bl, const float* __restrict__ br,
        __half* __restrict__ xl_h, __half* __restrict__ xr_h) {
    int w = threadIdx.x >> 6, lane = threadIdx.x & 63;
    int quad = lane >> 4, r16 = lane & 15;
    int m0 = blockIdx.x * 16;
    const _Float16* xrow = reinterpret_cast<const _Float16*>(xh) + (size_t)(m0 + r16) * D + quad * 8;
    half8 a[4];
    #pragma unroll
    for (int kt = 0; kt < 4; ++kt) a[kt] = *reinterpret_cast<const half8*>(xrow + kt * 32);
    f32x4 acc[4];
    #pragma unroll
    for (int nt = 0; nt < 4; ++nt) { f32x4 z = {0.f, 0.f, 0.f, 0.f}; acc[nt] = z; }
    #pragma unroll
    for (int nt = 0; nt < 4; ++nt) {
        int ntile = w * 4 + nt;
        #pragma unroll
        for (int kt = 0; kt < 4; ++kt) {
            half8 b = *reinterpret_cast<const half8*>(
                wfrag + ((size_t)(kt * 16 + ntile) * 64 + lane) * 8);
            acc[nt] = __builtin_amdgcn_mfma_f32_16x16x32_f16(a[kt], b, acc[nt], 0, 0, 0);
        }
    }
    #pragma unroll
    for (int nt = 0; nt < 4; ++nt) {
        int n = (w * 4 + nt) * 16 + r16;
        float bias = (n < 128) ? bl[n] : br[n - 128];
        #pragma unroll
        for (int r = 0; r < 4; ++r) {
            int node = m0 + quad * 4 + r;
            float v = acc[nt][r] + bias;
            if (n < 128) xl_h[(size_t)node * D + n] = __float2half_rn(v);
            else         xr_h[(size_t)node * D + (n - 128)] = __float2half_rn(v);
        }
    }
}

// One wave per node (2 nodes / 128-block). Thread = 2 channels. Online segment-softmax.
// Wave-cooperative src staging: one coalesced load covers up to 64 edges; per-edge
// broadcast via __shfl (DS) so gathers have no VMEM->VMEM dependency.
__global__ __launch_bounds__(128) void aggregate_kernel(
        const __half* __restrict__ xl_h, const __half* __restrict__ xr_h,
        const __half* __restrict__ loopm, const float* __restrict__ selff,
        const int* __restrict__ csr_off, const int* __restrict__ csr_src,
        const __half* __restrict__ csr_ea,
        const _Float16* __restrict__ Mh, const float* __restrict__ cfold,
        const float* __restrict__ att, const float* __restrict__ gbias,
        const float* __restrict__ bn_gamma, const float* __restrict__ bn_beta,
        __half* __restrict__ xout) {
    int n = blockIdx.x * 2 + (threadIdx.x >> 6);
    int t = threadIdx.x & 63;        // lane in wave
    int c0 = t * 2;                  // channels c0, c0+1; head = t>>3 (8 lanes/head)
    const char* xlb = reinterpret_cast<const char*>(xl_h);
    int lb = t << 2;                 // lane byte offset within a row (2 ch * 2 B)
    float att0 = att[c0], att1 = att[c0 + 1];
    H4 m0u, m1u;
    m0u.f4 = *reinterpret_cast<const float4*>(Mh + (size_t)c0 * 8);
    m1u.f4 = *reinterpret_cast<const float4*>(Mh + (size_t)(c0 + 1) * 8);
    float cf0 = cfold[c0], cf1 = cfold[c0 + 1];
    float2 xrv = __half22float2(*reinterpret_cast<const __half2*>(xr_h + (size_t)n * D + c0));
    float2 xlv = __half22float2(*reinterpret_cast<const __half2*>(xl_h + (size_t)n * D + c0));

    // self loop (edge attr = per-node mean of incoming raw attrs, fp16)
    H4 lau;
    lau.f4 = *reinterpret_cast<const float4*>(loopm + (size_t)n * 8);
    float sf = selff[n];
    float ep0 = cf0 * sf, ep1 = cf1 * sf;
    #pragma unroll
    for (int k = 0; k < 4; ++k) { ep0 = FDOT2(lau.h[k], m0u.h[k], ep0); ep1 = FDOT2(lau.h[k], m1u.h[k], ep1); }
    float z0 = xlv.x + xrv.x + ep0; z0 = fmaxf(z0, 0.2f * z0);
    float z1 = xlv.y + xrv.y + ep1; z1 = fmaxf(z1, 0.2f * z1);
    float lg = z0 * att0 + z1 * att1;
    lg += __shfl_xor(lg, 1); lg += __shfl_xor(lg, 2); lg += __shfl_xor(lg, 4);
    float m = lg, denom = 1.0f, acc0 = xlv.x, acc1 = xlv.y;

    int beg = csr_off[n], end = csr_off[n + 1];
    for (int base = beg; base < end; base += 64) {
        int cnt = end - base; if (cnt > 64) cnt = 64;
        int sreg = (t < cnt) ? csr_src[base + t] : 0;   // coalesced; byte row offsets
        int i = 0;
        for (; i + 4 <= cnt; i += 4) {
            int o0 = __shfl(sreg, i),     o1 = __shfl(sreg, i + 1);
            int o2 = __shfl(sreg, i + 2), o3 = __shfl(sreg, i + 3);
            __half2 g0 = *reinterpret_cast<const __half2*>(xlb + o0 + lb);
            __half2 g1 = *reinterpret_cast<const __half2*>(xlb + o1 + lb);
            __half2 g2 = *reinterpret_cast<const __half2*>(xlb + o2 + lb);
            __half2 g3 = *reinterpret_cast<const __half2*>(xlb + o3 + lb);
            H4 e0u, e1u, e2u, e3u;
            e0u.f4 = *reinterpret_cast<const float4*>(csr_ea + (size_t)(base + i) * 8);
            e1u.f4 = *reinterpret_cast<const float4*>(csr_ea + (size_t)(base + i) * 8 + 8);
            e2u.f4 = *reinterpret_cast<const float4*>(csr_ea + (size_t)(base + i) * 8 + 16);
            e3u.f4 = *reinterpret_cast<const float4*>(csr_ea + (size_t)(base + i) * 8 + 24);
            float p00 = cf0, p01 = cf1, p10 = cf0, p11 = cf1;
            float p20 = cf0, p21 = cf1, p30 = cf0, p31 = cf1;
            #pragma unroll
            for (int k = 0; k < 4; ++k) {
                p00 = FDOT2(e0u.h[k], m0u.h[k], p00); p01 = FDOT2(e0u.h[k], m1u.h[k], p01);
                p10 = FDOT2(e1u.h[k], m0u.h[k], p10); p11 = FDOT2(e1u.h[k], m1u.h[k], p11);
                p20 = FDOT2(e2u.h[k], m0u.h[k], p20); p21 = FDOT2(e2u.h[k], m1u.h[k], p21);
                p30 = FDOT2(e3u.h[k], m0u.h[k], p30); p31 = FDOT2(e3u.h[k], m1u.h[k], p31);
            }
            float2 x0 = __half22float2(g0), x1 = __half22float2(g1);
            float2 x2 = __half22float2(g2), x3 = __half22float2(g3);
            float za, zb, l0, l1, l2, l3;
            za = x0.x + xrv.x + p00; za = fmaxf(za, 0.2f * za);
            zb = x0.y + xrv.y + p01; zb = fmaxf(zb, 0.2f * zb);
            l0 = za * att0 + zb * att1;
            za = x1.x + xrv.x + p10; za = fmaxf(za, 0.2f * za);
            zb = x1.y + xrv.y + p11; zb = fmaxf(zb, 0.2f * zb);
            l1 = za * att0 + zb * att1;
            za = x2.x + xrv.x + p20; za = fmaxf(za, 0.2f * za);
            zb = x2.y + xrv.y + p21; zb = fmaxf(zb, 0.2f * zb);
            l2 = za * att0 + zb * att1;
            za = x3.x + xrv.x + p30; za = fmaxf(za, 0.2f * za);
            zb = x3.y + xrv.y + p31; zb = fmaxf(zb, 0.2f * zb);
            l3 = za * att0 + zb * att1;
            l0 += __shfl_xor(l0, 1); l0 += __shfl_xor(l0, 2); l0 += __shfl_xor(l0, 4);
            l1 += __shfl_xor(l1, 1); l1 += __shfl_xor(l1, 2); l1 += __shfl_xor(l1, 4);
            l2 += __shfl_xor(l2, 1); l2 += __shfl_xor(l2, 2); l2 += __shfl_xor(l2, 4);
            l3 += __shfl_xor(l3, 1); l3 += __shfl_xor(l3, 2); l3 += __shfl_xor(l3, 4);
            float nm = fmaxf(fmaxf(m, fmaxf(l0, l1)), fmaxf(l2, l3));
            float wo = __expf(m - nm);
            float w0 = __expf(l0 - nm), w1 = __expf(l1 - nm);
            float w2 = __expf(l2 - nm), w3 = __expf(l3 - nm);
            denom = denom * wo + (w0 + w1) + (w2 + w3);
            acc0 = acc0 * wo + w0 * x0.x + w1 * x1.x + w2 * x2.x + w3 * x3.x;
            acc1 = acc1 * wo + w0 * x0.y + w1 * x1.y + w2 * x2.y + w3 * x3.y;
            m = nm;
        }
        for (; i < cnt; ++i) {
            int o0 = __shfl(sreg, i);
            __half2 g0 = *reinterpret_cast<const __half2*>(xlb + o0 + lb);
            H4 e0u;
            e0u.f4 = *reinterpret_cast<const float4*>(csr_ea + (size_t)(base + i) * 8);
            float p00 = cf0, p01 = cf1;
            #pragma unroll
            for (int k = 0; k < 4; ++k) { p00 = FDOT2(e0u.h[k], m0u.h[k], p00); p01 = FDOT2(e0u.h[k], m1u.h[k], p01); }
            float2 x0 = __half22float2(g0);
            float za = x0.x + xrv.x + p00; za = fmaxf(za, 0.2f * za);
            float zb = x0.y + xrv.y + p01; zb = fmaxf(zb, 0.2f * zb);
            float l0 = za * att0 + zb * att1;
            l0 += __shfl_xor(l0, 1); l0 += __shfl_xor(l0, 2); l0 += __shfl_xor(l0, 4);
            float nm = fmaxf(m, l0);
            float wo = __expf(m - nm), w0 = __expf(l0 - nm);
            denom = denom * wo + w0;
            acc0 = acc0 * wo + w0 * x0.x;
            acc1 = acc1 * wo + w0 * x0.y;
            m = nm;
        }
    }
    float inv = 1.0f / denom;
    float h0 = acc0 * inv + gbias[c0];
    float h1 = acc1 * inv + gbias[c0 + 1];
    h0 = bn_gamma[c0] * h0 * 0.999995000037499813f + bn_beta[c0];
    h1 = bn_gamma[c0 + 1] * h1 * 0.999995000037499813f + bn_beta[c0 + 1];
    h0 = h0 > 0.f ? h0 : (__expf(h0) - 1.0f);
    h1 = h1 > 0.f ? h1 : (__expf(h1) - 1.0f);
    *reinterpret_cast<__half2*>(xout + (size_t)n * D + c0) = __floats2half2_rn(h0, h1);
}

__device__ __forceinline__ int lower_bound_dev(const int* a, int n, int v) {
    int lo = 0, hi = n;
    while (lo < hi) { int mid = (lo + hi) >> 1; if (a[mid] < v) lo = mid + 1; else hi = mid; }
    return lo;
}

// fused global mean pool + classifier head; batch sorted -> per-graph ranges, no atomics
__global__ __launch_bounds__(128) void headpool_kernel(
        const __half* __restrict__ xh, const int* __restrict__ batch,
        const float* __restrict__ hW, const float* __restrict__ hb,
        float* __restrict__ out) {
    __shared__ float lds[128];
    int g = blockIdx.x, t = threadIdx.x;
    int lo = lower_bound_dev(batch, N, g);
    int hi = lower_bound_dev(batch, N, g + 1);
    float s = 0.f;
    #pragma unroll 4
    for (int i = lo; i < hi; ++i) s += __half2float(xh[(size_t)i * D + t]);
    int c = hi - lo;
    lds[t] = s / (float)(c > 1 ? c : 1);
    __syncthreads();
    if (t < NC) {
        float p = hb[t];
        #pragma unroll 8
        for (int cc = 0; cc < D; ++cc) p += lds[cc] * hW[cc * NC + t];
        out[g * NC + t] = p;
    }
}

extern "C" void kernel_launch(void* const* d_in, const int* in_sizes, int n_in,
                              void* d_out, int out_size, void* d_ws, size_t ws_size,
                              hipStream_t stream) {
    const int*   x_nodes   = (const int*)  d_in[0];
    const int*   edge_src  = (const int*)  d_in[1];
    const int*   edge_dst  = (const int*)  d_in[2];
    const float* edge_attr = (const float*)d_in[3];
    const int*   batch     = (const int*)  d_in[4];
    const float* node_emb  = (const float*)d_in[5];
    const float* edge_W    = (const float*)d_in[6];
    const float* edge_b    = (const float*)d_in[7];
    const float* Wl        = (const float*)d_in[8];
    const float* bl        = (const float*)d_in[9];
    const float* Wr        = (const float*)d_in[10];
    const float* br        = (const float*)d_in[11];
    const float* We        = (const float*)d_in[12];
    const float* att       = (const float*)d_in[13];
    const float* gbias     = (const float*)d_in[14];
    const float* bn_gamma  = (const float*)d_in[15];
    const float* bn_beta   = (const float*)d_in[16];
    const float* head_W    = (const float*)d_in[17];
    const float* head_b    = (const float*)d_in[18];
    float* out = (float*)d_out;

    float* ws = (float*)d_ws;
    int*    cnt      = (int*)(ws + O_CNT);
    int*    cursor   = (int*)(ws + O_CURSOR);
    int*    csr_off  = (int*)(ws + O_CSROFF);
    int*    bsum     = (int*)(ws + O_BSUM);
    int*    csr_src  = (int*)(ws + O_CSRSRC);
    __half* csr_ea   = (__half*)(ws + O_CSREA);
    _Float16* Mh     = (_Float16*)(ws + O_MH);
    float*  cfold    = ws + O_CFOLD;
    __half* loopm    = (__half*)(ws + O_LOOPM);
    float*  selff    = ws + O_SELFF;
    _Float16* wfrag  = (_Float16*)(ws + O_WFRAG);
    __half* xh   = (__half*)(ws + O_XH);
    __half* xl_h = (__half*)(ws + O_XLH);
    __half* xr_h = (__half*)(ws + O_XRH);

    // 1) fused prep: embed + zero + weight-fragment cvt + edge-proj fold
    prep_kernel<<<PB_TOTAL, 256, 0, stream>>>(x_nodes, node_emb, xh, ws,
                                              Wl, Wr, wfrag, edge_W, edge_b, We, Mh, cfold);
    // 2) per-dst degree
    edge_cnt_kernel<<<(E + 255) / 256, 256, 0, stream>>>(edge_src, edge_dst, cnt);
    // 3) exclusive scan -> csr_off
    {
        int nb = (N + 1023) / 1024;   // 49
        scan1_kernel<<<nb, 256, 0, stream>>>(cnt, csr_off + 1, bsum);
        scan3_kernel<<<(N + 255) / 256, 256, 0, stream>>>(csr_off, bsum);
    }
    // 4) CSR scatter (byte-offset src + fp16 edge attrs inline)
    csr_fill_kernel<<<(E + 255) / 256, 256, 0, stream>>>(edge_src, edge_dst, edge_attr,
                                                         csr_off, cursor, csr_src, csr_ea);
    // 5) per-node mean edge attr + self-loop flag (fp16)
    loopmean_kernel<<<(N * 8 + 255) / 256, 256, 0, stream>>>(csr_off, csr_ea, loopm, selff);
    // 6) GAT layers
    for (int l = 0; l < L; ++l) {
        transform_kernel<<<N / 16, 256, 0, stream>>>(
            xh, wfrag + (size_t)l * 32768, bl + l * D, br + l * D, xl_h, xr_h);
        aggregate_kernel<<<N / 2, 128, 0, stream>>>(
            xl_h, xr_h, loopm, selff, csr_off, csr_src, csr_ea,
            Mh + (size_t)l * D * 8, cfold + l * D, att + l * D, gbias + l * D,
            bn_gamma + l * D, bn_beta + l * D, xh);
    }
    // 7) fused mean-pool + head
    headpool_kernel<<<G, 128, 0, stream>>>(xh, batch, head_W, head_b, out);

    (void)in_sizes; (void)n_in; (void)out_size; (void)ws_size;
}

// Round 6
// 532.922 us; speedup vs baseline: 2.9012x; 1.0826x over previous
//
#include <hip/hip_runtime.h>
#include <hip/hip_fp16.h>
#include <math.h>

static constexpr int N  = 50000;
static constexpr int E  = 800000;
static constexpr int G  = 512;
static constexpr int D  = 128;
static constexpr int EF = 8;
static constexpr int EE = 64;
static constexpr int L  = 4;
static constexpr int NC = 10;

typedef _Float16 half8 __attribute__((ext_vector_type(8)));
typedef _Float16 h2v  __attribute__((ext_vector_type(2)));
typedef float f2v __attribute__((ext_vector_type(2)));
typedef float f32x4 __attribute__((ext_vector_type(4)));

union H4 { float4 f4; h2v h[4]; };

#if __has_builtin(__builtin_amdgcn_fdot2)
#define FDOT2(a, b, c) __builtin_amdgcn_fdot2((a), (b), (c), false)
#else
#define FDOT2(a, b, c) ((float)(a)[0]*(float)(b)[0] + (float)(a)[1]*(float)(b)[1] + (c))
#endif

__device__ __forceinline__ h2v pkrtz(float a, float b) {
    return (h2v)__builtin_amdgcn_cvt_pkrtz(a, b);
}
__device__ __forceinline__ h2v hmax2(h2v a, h2v b) {
#if __has_builtin(__builtin_elementwise_max)
    return __builtin_elementwise_max(a, b);
#else
    h2v r; r[0] = a[0] > b[0] ? a[0] : b[0]; r[1] = a[1] > b[1] ? a[1] : b[1]; return r;
#endif
}
__device__ __forceinline__ h2v hfma2(h2v a, h2v b, h2v c) {
#if __has_builtin(__builtin_elementwise_fma)
    return __builtin_elementwise_fma(a, b, c);
#else
    return a * b + c;
#endif
}
// sum over 8-lane head group (lanes t, t^1, t^2, t^4) via DPP — no LDS traffic
__device__ __forceinline__ float red8(float v) {
#if __has_builtin(__builtin_amdgcn_update_dpp)
    v += __builtin_bit_cast(float, __builtin_amdgcn_update_dpp(
            0, __builtin_bit_cast(int, v), 0xB1, 0xF, 0xF, true));   // quad_perm [1,0,3,2] : xor1
    v += __builtin_bit_cast(float, __builtin_amdgcn_update_dpp(
            0, __builtin_bit_cast(int, v), 0x4E, 0xF, 0xF, true));   // quad_perm [2,3,0,1] : xor2
    v += __builtin_bit_cast(float, __builtin_amdgcn_update_dpp(
            0, __builtin_bit_cast(int, v), 0x141, 0xF, 0xF, true));  // row_half_mirror : cross-quad
#else
    v += __shfl_xor(v, 1); v += __shfl_xor(v, 2); v += __shfl_xor(v, 4);
#endif
    return v;
}

#define LOG2E 1.44269504088896340736f

static constexpr size_t pad64(size_t w){ return (w + 63) & ~size_t(63); }
// workspace layout in 4-byte words; [0, ZERO_END) is zero-initialized by prep
static constexpr size_t O_CNT     = 0;                               // N ints
static constexpr size_t O_CURSOR  = O_CNT + pad64(N);                // N ints
static constexpr size_t ZERO_END  = O_CURSOR + pad64(N);
static constexpr size_t O_CSROFF  = ZERO_END;                        // N+1 ints
static constexpr size_t O_BSUM    = O_CSROFF + pad64(N+1);           // 64 ints
static constexpr size_t O_CSRSRC  = O_BSUM + 64;                     // E ints (row BYTE offsets)
static constexpr size_t O_CSREA   = O_CSRSRC + pad64(E);             // E*8 halfs = E*4 words
static constexpr size_t O_MH      = O_CSREA + pad64((size_t)E*4);    // L*D*8 halfs = L*512 words
static constexpr size_t O_CFOLD   = O_MH + pad64((size_t)L*512);     // L*D f32
static constexpr size_t O_LOOPM   = O_CFOLD + pad64(L*D);            // N*8 halfs = N*4 words
static constexpr size_t O_SELFF   = O_LOOPM + pad64((size_t)N*4);    // N f32
static constexpr size_t O_WFRAG   = O_SELFF + pad64(N);              // L*32768 halfs
static constexpr size_t O_XH      = O_WFRAG + pad64((size_t)L*16384);// N*D halfs
static constexpr size_t O_XLH     = O_XH  + pad64((size_t)N*64);
static constexpr size_t O_XRH     = O_XLH + pad64((size_t)N*64);

// prep grid partition (256-thread blocks)
static constexpr int PB_EMB  = (N * D) / 256;                 // 25000
static constexpr int PB_ZERO = ((int)ZERO_END + 255) / 256;
static constexpr int PB_WCVT = (L * 32768) / 256;             // 512
static constexpr int PB_FOLD = L;                             // 4
static constexpr int PB_TOTAL = PB_EMB + PB_ZERO + PB_WCVT + PB_FOLD;

// fused: embed (fp16) | zero | wcvt (fragment-ordered weights) | fold (edge proj fold, fp16)
__global__ __launch_bounds__(256) void prep_kernel(
        const int* __restrict__ xn, const float* __restrict__ emb, __half* __restrict__ xh,
        float* __restrict__ zbase,
        const float* __restrict__ Wl, const float* __restrict__ Wr, _Float16* __restrict__ wfrag,
        const float* __restrict__ edge_W, const float* __restrict__ edge_b,
        const float* __restrict__ We, _Float16* __restrict__ Mh, float* __restrict__ cfold) {
    int bid = blockIdx.x, t = threadIdx.x;
    if (bid < PB_EMB) {
        int i = bid * 256 + t;                     // N*D
        int n = i >> 7, c = i & 127;
        xh[i] = __float2half_rn(emb[xn[n] * D + c]);
    } else if (bid < PB_EMB + PB_ZERO) {
        int i = (bid - PB_EMB) * 256 + t;
        if (i < (int)ZERO_END) zbase[i] = 0.0f;
    } else if (bid < PB_EMB + PB_ZERO + PB_WCVT) {
        int i = (bid - PB_EMB - PB_ZERO) * 256 + t; // L*32768
        int j    = i & 7;
        int lane = (i >> 3) & 63;
        int nt   = (i >> 9) & 15;
        int kt   = (i >> 13) & 3;
        int l    = i >> 15;
        int k = kt * 32 + (lane >> 4) * 8 + j;
        int n = nt * 16 + (lane & 15);
        float v = (n < 128) ? Wl[((size_t)l * D + k) * D + n]
                            : Wr[((size_t)l * D + k) * D + (n - 128)];
        wfrag[i] = (_Float16)v;
    } else {
        int l = bid - PB_EMB - PB_ZERO - PB_WCVT;  // 4 blocks
        if (t >= 128) return;
        const float* Wel = We + (size_t)l * EE * D;
        for (int j = 0; j < EF; ++j) {
            float s = 0.f;
            for (int k = 0; k < EE; ++k) s += edge_W[j * EE + k] * Wel[k * D + t];
            Mh[((size_t)l * D + t) * 8 + j] = (_Float16)s;   // [l][c][j]
        }
        float s = 0.f;
        for (int k = 0; k < EE; ++k) s += edge_b[k] * Wel[k * D + t];
        cfold[l * D + t] = s;
    }
}

__global__ void edge_cnt_kernel(const int* __restrict__ src, const int* __restrict__ dst,
                                int* __restrict__ cnt) {
    int e = blockIdx.x * blockDim.x + threadIdx.x;
    if (e >= E) return;
    if (src[e] != dst[e]) atomicAdd(&cnt[dst[e]], 1);
}

__global__ void scan1_kernel(const int* __restrict__ cnt, int* __restrict__ out /*=csr_off+1*/,
                             int* __restrict__ bsum) {
    __shared__ int lds[256];
    int b = blockIdx.x, t = threadIdx.x;
    int base = b * 1024 + t * 4;
    int v[4]; int s = 0;
    #pragma unroll
    for (int k = 0; k < 4; ++k) { int idx = base + k; v[k] = (idx < N) ? cnt[idx] : 0; s += v[k]; }
    lds[t] = s; __syncthreads();
    for (int off = 1; off < 256; off <<= 1) {
        int add = (t >= off) ? lds[t - off] : 0;
        __syncthreads();
        lds[t] += add;
        __syncthreads();
    }
    int run = (t > 0) ? lds[t - 1] : 0;
    #pragma unroll
    for (int k = 0; k < 4; ++k) { run += v[k]; int idx = base + k; if (idx < N) out[idx] = run; }
    if (t == 255) bsum[b] = lds[255];
}

__global__ void scan3_kernel(int* __restrict__ csr_off, const int* __restrict__ bsum) {
    int i = blockIdx.x * blockDim.x + threadIdx.x;
    if (i == 0) csr_off[0] = 0;
    if (i >= N) return;
    int b = i >> 10;
    int add = 0;
    for (int k = 0; k < b; ++k) add += bsum[k];
    csr_off[1 + i] += add;
}

__global__ void csr_fill_kernel(const int* __restrict__ src, const int* __restrict__ dst,
                                const float* __restrict__ eattr,
                                const int* __restrict__ csr_off, int* __restrict__ cursor,
                                int* __restrict__ csr_src, __half* __restrict__ csr_ea) {
    int e = blockIdx.x * blockDim.x + threadIdx.x;
    if (e >= E) return;
    int s = src[e], d = dst[e];
    if (s == d) return;
    int pos = csr_off[d] + atomicAdd(&cursor[d], 1);
    csr_src[pos] = s << 8;   // byte offset of row s (128 ch * 2 B)
    const float4* p = reinterpret_cast<const float4*>(eattr + (size_t)e * 8);
    float4 a = p[0], b = p[1];
    __half2 h[4];
    h[0] = __floats2half2_rn(a.x, a.y); h[1] = __floats2half2_rn(a.z, a.w);
    h[2] = __floats2half2_rn(b.x, b.y); h[3] = __floats2half2_rn(b.z, b.w);
    *reinterpret_cast<float4*>(csr_ea + (size_t)pos * 8) = *reinterpret_cast<const float4*>(h);
}

__global__ void loopmean_kernel(const int* __restrict__ csr_off, const __half* __restrict__ csr_ea,
                                __half* __restrict__ loopm, float* __restrict__ selff) {
    int i = blockIdx.x * blockDim.x + threadIdx.x;   // N*8
    int n = i >> 3, j = i & 7;
    if (n >= N) return;
    int beg = csr_off[n], end = csr_off[n + 1];
    float s = 0.f;
    for (int idx = beg; idx < end; ++idx) s += __half2float(csr_ea[(size_t)idx * 8 + j]);
    int c = end - beg;
    loopm[(size_t)n * 8 + j] = __float2half_rn(s / (float)(c > 1 ? c : 1));
    if (j == 0) selff[n] = (c > 0) ? 1.0f : 0.0f;
}

// [xl|xr] = x @ [Wl|Wr] + [bl|br] via f16 MFMA. Block=256 (4 waves), 16 nodes/block.
__global__ __launch_bounds__(256) void transform_kernel(
        const __half* __restrict__ xh, const _Float16* __restrict__ wfrag,
        const float* __restrict__ bl, const float* __restrict__ br,
        __half* __restrict__ xl_h, __half* __restrict__ xr_h) {
    int w = threadIdx.x >> 6, lane = threadIdx.x & 63;
    int quad = lane >> 4, r16 = lane & 15;
    int m0 = blockIdx.x * 16;
    const _Float16* xrow = reinterpret_cast<const _Float16*>(xh) + (size_t)(m0 + r16) * D + quad * 8;
    half8 a[4];
    #pragma unroll
    for (int kt = 0; kt < 4; ++kt) a[kt] = *reinterpret_cast<const half8*>(xrow + kt * 32);
    f32x4 acc[4];
    #pragma unroll
    for (int nt = 0; nt < 4; ++nt) { f32x4 z = {0.f, 0.f, 0.f, 0.f}; acc[nt] = z; }
    #pragma unroll
    for (int nt = 0; nt < 4; ++nt) {
        int ntile = w * 4 + nt;
        #pragma unroll
        for (int kt = 0; kt < 4; ++kt) {
            half8 b = *reinterpret_cast<const half8*>(
                wfrag + ((size_t)(kt * 16 + ntile) * 64 + lane) * 8);
            acc[nt] = __builtin_amdgcn_mfma_f32_16x16x32_f16(a[kt], b, acc[nt], 0, 0, 0);
        }
    }
    #pragma unroll
    for (int nt = 0; nt < 4; ++nt) {
        int n = (w * 4 + nt) * 16 + r16;
        float bias = (n < 128) ? bl[n] : br[n - 128];
        #pragma unroll
        for (int r = 0; r < 4; ++r) {
            int node = m0 + quad * 4 + r;
            float v = acc[nt][r] + bias;
            if (n < 128) xl_h[(size_t)node * D + n] = __float2half_rn(v);
            else         xr_h[(size_t)node * D + (n - 128)] = __float2half_rn(v);
        }
    }
}

// One wave per node (64-thread block). Thread = 2 channels (packed fp16 math).
// Projection in f32 fdot2, z/leaky/logit in pk-f16, logits in log2 domain (exp2),
// fp16 packed accumulator, DPP head-reduce.
__global__ __launch_bounds__(64) void aggregate_kernel(
        const __half* __restrict__ xl_h, const __half* __restrict__ xr_h,
        const __half* __restrict__ loopm, const float* __restrict__ selff,
        const int* __restrict__ csr_off, const int* __restrict__ csr_src,
        const __half* __restrict__ csr_ea,
        const _Float16* __restrict__ Mh, const float* __restrict__ cfold,
        const float* __restrict__ att, const float* __restrict__ gbias,
        const float* __restrict__ bn_gamma, const float* __restrict__ bn_beta,
        __half* __restrict__ xout) {
    int n = blockIdx.x;
    int t = threadIdx.x;             // lane in wave
    int c0 = t * 2;                  // channels c0, c0+1; head = t>>3 (8 lanes/head)
    const char* xlb = reinterpret_cast<const char*>(xl_h);
    int lb = t << 2;                 // lane byte offset within a row (2 ch * 2 B)
    h2v attp = pkrtz(att[c0] * LOG2E, att[c0 + 1] * LOG2E);
    H4 m0u, m1u;
    m0u.f4 = *reinterpret_cast<const float4*>(Mh + (size_t)c0 * 8);
    m1u.f4 = *reinterpret_cast<const float4*>(Mh + (size_t)(c0 + 1) * 8);
    float cf0 = cfold[c0], cf1 = cfold[c0 + 1];
    h2v xrp = *reinterpret_cast<const h2v*>(xr_h + (size_t)n * D + c0);
    h2v xlp = *reinterpret_cast<const h2v*>(xl_h + (size_t)n * D + c0);
    const h2v c02 = {(_Float16)0.2f, (_Float16)0.2f};

    // self loop (edge attr = per-node mean of incoming raw attrs, fp16)
    H4 lau;
    lau.f4 = *reinterpret_cast<const float4*>(loopm + (size_t)n * 8);
    float sf = selff[n];
    float ep0 = cf0 * sf, ep1 = cf1 * sf;
    #pragma unroll
    for (int k = 0; k < 4; ++k) { ep0 = FDOT2(lau.h[k], m0u.h[k], ep0); ep1 = FDOT2(lau.h[k], m1u.h[k], ep1); }
    {
        f2v xlf = __builtin_convertvector(xlp, f2v);
        f2v xrf = __builtin_convertvector(xrp, f2v);
        float z0 = xlf[0] + xrf[0] + ep0; z0 = fmaxf(z0, 0.2f * z0);
        float z1 = xlf[1] + xrf[1] + ep1; z1 = fmaxf(z1, 0.2f * z1);
        ep0 = FDOT2(pkrtz(z0, z1), attp, 0.0f);
    }
    float m = red8(ep0);
    float denom = 1.0f;
    h2v acc = xlp;

    int beg = csr_off[n], end = csr_off[n + 1];
    for (int base = beg; base < end; base += 64) {
        int cnt = end - base; if (cnt > 64) cnt = 64;
        int sreg = (t < cnt) ? csr_src[base + t] : 0;   // coalesced; byte row offsets
        int i = 0;
        for (; i + 4 <= cnt; i += 4) {
            int o0 = __shfl(sreg, i),     o1 = __shfl(sreg, i + 1);
            int o2 = __shfl(sreg, i + 2), o3 = __shfl(sreg, i + 3);
            h2v g0 = *reinterpret_cast<const h2v*>(xlb + o0 + lb);
            h2v g1 = *reinterpret_cast<const h2v*>(xlb + o1 + lb);
            h2v g2 = *reinterpret_cast<const h2v*>(xlb + o2 + lb);
            h2v g3 = *reinterpret_cast<const h2v*>(xlb + o3 + lb);
            H4 e0u, e1u, e2u, e3u;
            e0u.f4 = *reinterpret_cast<const float4*>(csr_ea + (size_t)(base + i) * 8);
            e1u.f4 = *reinterpret_cast<const float4*>(csr_ea + (size_t)(base + i) * 8 + 8);
            e2u.f4 = *reinterpret_cast<const float4*>(csr_ea + (size_t)(base + i) * 8 + 16);
            e3u.f4 = *reinterpret_cast<const float4*>(csr_ea + (size_t)(base + i) * 8 + 24);
            float p00 = cf0, p01 = cf1, p10 = cf0, p11 = cf1;
            float p20 = cf0, p21 = cf1, p30 = cf0, p31 = cf1;
            #pragma unroll
            for (int k = 0; k < 4; ++k) {
                p00 = FDOT2(e0u.h[k], m0u.h[k], p00); p01 = FDOT2(e0u.h[k], m1u.h[k], p01);
                p10 = FDOT2(e1u.h[k], m0u.h[k], p10); p11 = FDOT2(e1u.h[k], m1u.h[k], p11);
                p20 = FDOT2(e2u.h[k], m0u.h[k], p20); p21 = FDOT2(e2u.h[k], m1u.h[k], p21);
                p30 = FDOT2(e3u.h[k], m0u.h[k], p30); p31 = FDOT2(e3u.h[k], m1u.h[k], p31);
            }
            h2v z0 = g0 + xrp + pkrtz(p00, p01);
            h2v z1 = g1 + xrp + pkrtz(p10, p11);
            h2v z2 = g2 + xrp + pkrtz(p20, p21);
            h2v z3 = g3 + xrp + pkrtz(p30, p31);
            z0 = hmax2(z0, z0 * c02); z1 = hmax2(z1, z1 * c02);
            z2 = hmax2(z2, z2 * c02); z3 = hmax2(z3, z3 * c02);
            float l0 = red8(FDOT2(z0, attp, 0.0f));
            float l1 = red8(FDOT2(z1, attp, 0.0f));
            float l2 = red8(FDOT2(z2, attp, 0.0f));
            float l3 = red8(FDOT2(z3, attp, 0.0f));
            float gm = fmaxf(fmaxf(l0, l1), fmaxf(l2, l3));
            float nm = fmaxf(m, gm);
            float wo = __builtin_amdgcn_exp2f(m - nm);
            float w0 = __builtin_amdgcn_exp2f(l0 - nm);
            float w1 = __builtin_amdgcn_exp2f(l1 - nm);
            float w2 = __builtin_amdgcn_exp2f(l2 - nm);
            float w3 = __builtin_amdgcn_exp2f(l3 - nm);
            denom = denom * wo + (w0 + w1) + (w2 + w3);
            acc = acc * pkrtz(wo, wo);
            acc = hfma2(pkrtz(w0, w0), g0, acc);
            acc = hfma2(pkrtz(w1, w1), g1, acc);
            acc = hfma2(pkrtz(w2, w2), g2, acc);
            acc = hfma2(pkrtz(w3, w3), g3, acc);
            m = nm;
        }
        for (; i < cnt; ++i) {
            int o0 = __shfl(sreg, i);
            h2v g0 = *reinterpret_cast<const h2v*>(xlb + o0 + lb);
            H4 e0u;
            e0u.f4 = *reinterpret_cast<const float4*>(csr_ea + (size_t)(base + i) * 8);
            float p00 = cf0, p01 = cf1;
            #pragma unroll
            for (int k = 0; k < 4; ++k) { p00 = FDOT2(e0u.h[k], m0u.h[k], p00); p01 = FDOT2(e0u.h[k], m1u.h[k], p01); }
            h2v z0 = g0 + xrp + pkrtz(p00, p01);
            z0 = hmax2(z0, z0 * c02);
            float l0 = red8(FDOT2(z0, attp, 0.0f));
            float nm = fmaxf(m, l0);
            float wo = __builtin_amdgcn_exp2f(m - nm);
            float w0 = __builtin_amdgcn_exp2f(l0 - nm);
            denom = denom * wo + w0;
            acc = acc * pkrtz(wo, wo);
            acc = hfma2(pkrtz(w0, w0), g0, acc);
            m = nm;
        }
    }
    f2v accf = __builtin_convertvector(acc, f2v);
    float inv = 1.0f / denom;
    float h0 = accf[0] * inv + gbias[c0];
    float h1 = accf[1] * inv + gbias[c0 + 1];
    h0 = bn_gamma[c0] * h0 * 0.999995000037499813f + bn_beta[c0];
    h1 = bn_gamma[c0 + 1] * h1 * 0.999995000037499813f + bn_beta[c0 + 1];
    h0 = h0 > 0.f ? h0 : (__expf(h0) - 1.0f);
    h1 = h1 > 0.f ? h1 : (__expf(h1) - 1.0f);
    *reinterpret_cast<__half2*>(xout + (size_t)n * D + c0) = __floats2half2_rn(h0, h1);
}

__device__ __forceinline__ int lower_bound_dev(const int* a, int n, int v) {
    int lo = 0, hi = n;
    while (lo < hi) { int mid = (lo + hi) >> 1; if (a[mid] < v) lo = mid + 1; else hi = mid; }
    return lo;
}

__global__ __launch_bounds__(128) void headpool_kernel(
        const __half* __restrict__ xh, const int* __restrict__ batch,
        const float* __restrict__ hW, const float* __restrict__ hb,
        float* __restrict__ out) {
    __shared__ float lds[128];
    int g = blockIdx.x, t = threadIdx.x;
    int lo = lower_bound_dev(batch, N, g);
    int hi = lower_bound_dev(batch, N, g + 1);
    float s = 0.f;
    #pragma unroll 4
    for (int i = lo; i < hi; ++i) s += __half2float(xh[(size_t)i * D + t]);
    int c = hi - lo;
    lds[t] = s / (float)(c > 1 ? c : 1);
    __syncthreads();
    if (t < NC) {
        float p = hb[t];
        #pragma unroll 8
        for (int cc = 0; cc < D; ++cc) p += lds[cc] * hW[cc * NC + t];
        out[g * NC + t] = p;
    }
}

extern "C" void kernel_launch(void* const* d_in, const int* in_sizes, int n_in,
                              void* d_out, int out_size, void* d_ws, size_t ws_size,
                              hipStream_t stream) {
    const int*   x_nodes   = (const int*)  d_in[0];
    const int*   edge_src  = (const int*)  d_in[1];
    const int*   edge_dst  = (const int*)  d_in[2];
    const float* edge_attr = (const float*)d_in[3];
    const int*   batch     = (const int*)  d_in[4];
    const float* node_emb  = (const float*)d_in[5];
    const float* edge_W    = (const float*)d_in[6];
    const float* edge_b    = (const float*)d_in[7];
    const float* Wl        = (const float*)d_in[8];
    const float* bl        = (const float*)d_in[9];
    const float* Wr        = (const float*)d_in[10];
    const float* br        = (const float*)d_in[11];
    const float* We        = (const float*)d_in[12];
    const float* att       = (const float*)d_in[13];
    const float* gbias     = (const float*)d_in[14];
    const float* bn_gamma  = (const float*)d_in[15];
    const float* bn_beta   = (const float*)d_in[16];
    const float* head_W    = (const float*)d_in[17];
    const float* head_b    = (const float*)d_in[18];
    float* out = (float*)d_out;

    float* ws = (float*)d_ws;
    int*    cnt      = (int*)(ws + O_CNT);
    int*    cursor   = (int*)(ws + O_CURSOR);
    int*    csr_off  = (int*)(ws + O_CSROFF);
    int*    bsum     = (int*)(ws + O_BSUM);
    int*    csr_src  = (int*)(ws + O_CSRSRC);
    __half* csr_ea   = (__half*)(ws + O_CSREA);
    _Float16* Mh     = (_Float16*)(ws + O_MH);
    float*  cfold    = ws + O_CFOLD;
    __half* loopm    = (__half*)(ws + O_LOOPM);
    float*  selff    = ws + O_SELFF;
    _Float16* wfrag  = (_Float16*)(ws + O_WFRAG);
    __half* xh   = (__half*)(ws + O_XH);
    __half* xl_h = (__half*)(ws + O_XLH);
    __half* xr_h = (__half*)(ws + O_XRH);

    prep_kernel<<<PB_TOTAL, 256, 0, stream>>>(x_nodes, node_emb, xh, ws,
                                              Wl, Wr, wfrag, edge_W, edge_b, We, Mh, cfold);
    edge_cnt_kernel<<<(E + 255) / 256, 256, 0, stream>>>(edge_src, edge_dst, cnt);
    {
        int nb = (N + 1023) / 1024;   // 49
        scan1_kernel<<<nb, 256, 0, stream>>>(cnt, csr_off + 1, bsum);
        scan3_kernel<<<(N + 255) / 256, 256, 0, stream>>>(csr_off, bsum);
    }
    csr_fill_kernel<<<(E + 255) / 256, 256, 0, stream>>>(edge_src, edge_dst, edge_attr,
                                                         csr_off, cursor, csr_src, csr_ea);
    loopmean_kernel<<<(N * 8 + 255) / 256, 256, 0, stream>>>(csr_off, csr_ea, loopm, selff);
    for (int l = 0; l < L; ++l) {
        transform_kernel<<<N / 16, 256, 0, stream>>>(
            xh, wfrag + (size_t)l * 32768, bl + l * D, br + l * D, xl_h, xr_h);
        aggregate_kernel<<<N, 64, 0, stream>>>(
            xl_h, xr_h, loopm, selff, csr_off, csr_src, csr_ea,
            Mh + (size_t)l * D * 8, cfold + l * D, att + l * D, gbias + l * D,
            bn_gamma + l * D, bn_beta + l * D, xh);
    }
    headpool_kernel<<<G, 128, 0, stream>>>(xh, batch, head_W, head_b, out);

    (void)in_sizes; (void)n_in; (void)out_size; (void)ws_size;
}